// Round 11
// baseline (759.971 us; speedup 1.0000x reference)
//
#include <hip/hip_runtime.h>
#include <math.h>

constexpr float DELTA_ = 2.5f;
#define BN_BLOCKS 512
#define NPB 8   // nodes per k_agg block

typedef __attribute__((ext_vector_type(8))) short bf16x8;
typedef __attribute__((ext_vector_type(8))) _Float16 f16x8;
typedef __attribute__((ext_vector_type(4))) float f32x4;

__device__ inline ushort bf16h(float x){
  union { float f; unsigned u; } v; v.f = x;
  unsigned r = v.u + 0x7fffu + ((v.u >> 16) & 1u);
  return (ushort)(r >> 16);
}
__device__ inline float bf16f(ushort h){
  union { unsigned u; float f; } v; v.u = ((unsigned)h) << 16;
  return v.f;
}

// ---------- U-weights: Wpk2[t][192][320] bf16 (col = path*64+o; path1/2 zero h-rows) ----------
__global__ __launch_bounds__(256) void k_tU(const float* __restrict__ Uw, ushort* __restrict__ Wpk2){
  int i = blockIdx.x*256 + threadIdx.x;          // i = (t*192+col)*320 + k
  if (i >= 4*192*320) return;
  int k   = i % 320;
  int col = (i/320) % 192;
  int t   = i/(320*192);
  int path = col >> 6, o = col & 63;
  float v = 0.f;
  int src = -1;
  if (k < 64){ if (path == 0) src = k; }
  else        src = k + path*256;
  if (src >= 0) v = Uw[((size_t)(t*64 + o))*832 + src];
  Wpk2[i] = bf16h(v);
}

// ---------- mix weights: Wm2[col][256] bf16 ----------
__global__ __launch_bounds__(256) void k_tMm(const float* __restrict__ mixw, ushort* __restrict__ Wm2){
  int i = blockIdx.x*256 + threadIdx.x;
  if (i >= 256*256) return;
  Wm2[i] = bf16h(mixw[i]);
}

// ---------- W_ef in B-fragment layout: Wefp[(cb*64+lane)*8+j], ch=cb*16+(lane&15), k=(lane>>4)*8+j ----------
__global__ __launch_bounds__(256) void k_tE2(const float* __restrict__ Mw, _Float16* __restrict__ Wefp){
  int i = blockIdx.x*256 + threadIdx.x;
  if (i >= 16*64*8) return;
  int j    = i & 7;
  int lane = (i >> 3) & 63;
  int cb   = i >> 9;
  int ch = cb*16 + (lane & 15);
  int k  = ((lane >> 4) & 3)*8 + j;
  Wefp[i] = (_Float16)Mw[(size_t)ch*160 + 128 + k];
}

// ---------- X2 h-part: X2[n][t][j][hi8|lo8] for k=0..63 ----------
__global__ __launch_bounds__(256) void k_xh(const float* __restrict__ nf, ushort* __restrict__ X2, int N){
  for (long i = blockIdx.x*256 + threadIdx.x; i < (long)N*256; i += (long)gridDim.x*256){
    int n = (int)(i >> 8), c = (int)(i & 255);
    int t = c >> 6, d = c & 63;
    int j = d >> 3, pos = d & 7;
    float v = nf[i];
    ushort hi = bf16h(v);
    size_t base = (((size_t)n*4 + t)*40 + j)*16;
    X2[base + pos]     = hi;
    X2[base + 8 + pos] = bf16h(v - bf16f(hi));
  }
}

__global__ __launch_bounds__(256) void k_hist(const int* __restrict__ dstv, int* __restrict__ cnt, int E){
  int e = blockIdx.x*256 + threadIdx.x;
  if (e < E) atomicAdd(&cnt[dstv[e]], 1);
}

__global__ __launch_bounds__(256) void k_scan1(const int* __restrict__ cnt, int* __restrict__ offs,
                                               int* __restrict__ bsum, int N){
  __shared__ int lds[256];
  int i = threadIdx.x;
  int g = blockIdx.x*256 + i;
  int v = (g < N) ? cnt[g] : 0;
  int acc = v;
  lds[i] = acc; __syncthreads();
  for (int s = 1; s < 256; s <<= 1){
    int t = (i >= s) ? lds[i - s] : 0;
    __syncthreads();
    acc += t; lds[i] = acc;
    __syncthreads();
  }
  if (g < N) offs[g] = acc - v;
  if (i == 255) bsum[blockIdx.x] = acc;
}

__global__ __launch_bounds__(256) void k_scan2(int* __restrict__ bsum, int NB){
  __shared__ int lds[256];
  int i = threadIdx.x;
  int v = (i < NB) ? bsum[i] : 0;
  int acc = v;
  lds[i] = acc; __syncthreads();
  for (int s = 1; s < 256; s <<= 1){
    int t = (i >= s) ? lds[i - s] : 0;
    __syncthreads();
    acc += t; lds[i] = acc;
    __syncthreads();
  }
  if (i < NB) bsum[i] = acc - v;
}

__global__ __launch_bounds__(256) void k_scan3(int* __restrict__ offs, const int* __restrict__ bsum, int N, int E){
  int g = blockIdx.x*256 + threadIdx.x;
  if (g < N) offs[g] += bsum[blockIdx.x];
  if (g == 0) offs[N] = E;
}

__global__ __launch_bounds__(256) void k_fill(const int* __restrict__ dstv, const int* __restrict__ offs,
                                              int* __restrict__ cur, int* __restrict__ elist, int E){
  int e = blockIdx.x*256 + threadIdx.x;
  if (e < E){
    int d = dstv[e];
    elist[offs[d] + atomicAdd(&cur[d], 1)] = e;
  }
}

// ---------- permute srcv + edge features (f16) into CSR order ----------
__global__ __launch_bounds__(256) void k_perm(const int* __restrict__ elist, const int* __restrict__ srcv,
                                              const float* __restrict__ efeat,
                                              int* __restrict__ esrc, _Float16* __restrict__ efh, int E){
  int g = blockIdx.x*256 + threadIdx.x;
  int pos = g >> 3;
  int q   = g & 7;
  if (pos >= E) return;
  int e = elist[pos];
  if (q == 0) esrc[pos] = srcv[e];
  float4 v = *(const float4*)(efeat + (size_t)e*32 + q*4);
  union { ushort4 u; _Float16 h[4]; } cv;
  cv.h[0] = (_Float16)v.x; cv.h[1] = (_Float16)v.y;
  cv.h[2] = (_Float16)v.z; cv.h[3] = (_Float16)v.w;
  *(ushort4*)(efh + (size_t)pos*32 + q*4) = cv.u;
}

// ---------- A_h = f16(W_src*h), B = W_dst*h + M_b ----------
__global__ __launch_bounds__(256) void k_ab(const float* __restrict__ nf, const float* __restrict__ Mw,
                                            const float* __restrict__ Mb,
                                            _Float16* __restrict__ A_h, float* __restrict__ B, int N){
  int c = threadIdx.x;
  int t = __builtin_amdgcn_readfirstlane(threadIdx.x >> 6);
  float ws[64], wd[64];
  const float* row = Mw + (size_t)c*160;
#pragma unroll
  for (int k = 0; k < 64; k += 4){
    float4 a = *(const float4*)(row + k);
    float4 b = *(const float4*)(row + 64 + k);
    ws[k]=a.x; ws[k+1]=a.y; ws[k+2]=a.z; ws[k+3]=a.w;
    wd[k]=b.x; wd[k+1]=b.y; wd[k+2]=b.z; wd[k+3]=b.w;
  }
  float bias = Mb[c];
  for (int n = blockIdx.x; n < N; n += gridDim.x){
    const float* h = nf + (size_t)n*256 + t*64;
    float sa = 0.f, sb = 0.f;
#pragma unroll
    for (int k = 0; k < 64; k += 4){
      float4 h4 = *(const float4*)(h + k);
      sa = fmaf(ws[k], h4.x, sa);  sb = fmaf(wd[k], h4.x, sb);
      sa = fmaf(ws[k+1], h4.y, sa); sb = fmaf(wd[k+1], h4.y, sb);
      sa = fmaf(ws[k+2], h4.z, sa); sb = fmaf(wd[k+2], h4.z, sb);
      sa = fmaf(ws[k+3], h4.w, sa); sb = fmaf(wd[k+3], h4.w, sb);
    }
    A_h[(size_t)n*256 + c] = (_Float16)sa;
    B[(size_t)n*256 + c] = sb + bias;
  }
}

// ---------- aggregation: two-phase, 8 nodes/block ----------
// Phase A (per 64-edge window): waves cooperatively MFMA eproj[64][256] into LDS.
// Phase B: thread = channel c, walks window edges with uniform node-boundary
// finalization; m' = eproj + A_gather (b0 commuted out, validated r9).
// eps second dim MUST be >=256 (+pad): r10's [132] was an OOB bug (absmax 2.1).
__global__ __launch_bounds__(256) void k_agg(const int* __restrict__ offs, const int* __restrict__ esrc,
                                             const _Float16* __restrict__ efh,
                                             const _Float16* __restrict__ A_h, const float* __restrict__ B,
                                             const _Float16* __restrict__ Wefp,
                                             ushort* __restrict__ X2, float* __restrict__ sc, int N, int E){
  __shared__ float eps[64][260];
  int tid = threadIdx.x;
  int lane = tid & 63, wv = tid >> 6;
  int li = lane & 15, kq = lane >> 4;
  int c = tid;                                  // this thread's channel
  int tw = c >> 6, d = c & 63;                  // tower, within-tower channel

  int n0 = blockIdx.x * NPB;
  if (n0 >= N) return;
  int n1 = n0 + NPB; if (n1 > N) n1 = N;
  int oS = offs[n0], oE = offs[n1];

  f16x8 bf[4];
#pragma unroll
  for (int cbl = 0; cbl < 4; ++cbl)
    bf[cbl] = *(const f16x8*)(Wefp + ((size_t)(wv*4 + cbl)*64 + lane)*8);

  int cur = n0;
  int curstart = oS;
  int nextoff = offs[n0 + 1];
  float s = 0.f, ss = 0.f;
  float mx = -__builtin_huge_valf(), mn = __builtin_huge_valf();

#define FINALIZE(CNT)                                                             \
  {                                                                                \
    float b = B[(size_t)cur*256 + c];                                              \
    float deg = (float)(CNT);                                                      \
    float degc = fmaxf(deg, 1.f);                                                  \
    float inv = 1.f / degc;                                                        \
    float S  = fmaf(deg, b, s);                                                    \
    float SS = fmaf(deg, b*b, fmaf(2.f*b, s, ss));                                 \
    float mean = S * inv;                                                          \
    float var  = fmaxf(SS * inv - mean*mean, 0.f);                                 \
    float sd   = sqrtf(var + 1e-30f);                                              \
    float MX = ((CNT) > 0) ? (b + mx) : 0.f;                                       \
    float MN = ((CNT) > 0) ? (b + mn) : 0.f;                                       \
    size_t xb = (((size_t)cur*4 + tw)*40)*16;                                      \
    { int kk = 64 + d;       ushort h2 = bf16h(mean);                              \
      X2[xb + (kk>>3)*16 + (kk&7)] = h2;                                           \
      X2[xb + (kk>>3)*16 + 8 + (kk&7)] = bf16h(mean - bf16f(h2)); }                \
    { int kk = 128 + d;      ushort h2 = bf16h(MX);                                \
      X2[xb + (kk>>3)*16 + (kk&7)] = h2;                                           \
      X2[xb + (kk>>3)*16 + 8 + (kk&7)] = bf16h(MX - bf16f(h2)); }                  \
    { int kk = 192 + d;      ushort h2 = bf16h(MN);                                \
      X2[xb + (kk>>3)*16 + (kk&7)] = h2;                                           \
      X2[xb + (kk>>3)*16 + 8 + (kk&7)] = bf16h(MN - bf16f(h2)); }                  \
    { int kk = 256 + d;      ushort h2 = bf16h(sd);                                \
      X2[xb + (kk>>3)*16 + (kk&7)] = h2;                                           \
      X2[xb + (kk>>3)*16 + 8 + (kk&7)] = bf16h(sd - bf16f(h2)); }                  \
    if (tid == 0){                                                                 \
      float logd = logf(deg + 1.f);                                                \
      sc[(size_t)cur*2]     = logd * (1.f / DELTA_);                               \
      sc[(size_t)cur*2 + 1] = ((CNT) > 0) ? (DELTA_ / fmaxf(logd, 1e-12f)) : 0.f;  \
    }                                                                              \
  }

  for (int w0 = oS; w0 < oE; w0 += 64){
    // ---- phase A: eproj for edges [w0, w0+64) ----
    __syncthreads();
#pragma unroll
    for (int ch = 0; ch < 4; ++ch){
      int pos = w0 + ch*16 + li;
      if (pos > E - 1) pos = E - 1;
      f16x8 af = *(const f16x8*)(efh + (size_t)pos*32 + kq*8);
      f32x4 ep0 = __builtin_amdgcn_mfma_f32_16x16x32_f16(af, bf[0], (f32x4)0.f, 0, 0, 0);
      f32x4 ep1 = __builtin_amdgcn_mfma_f32_16x16x32_f16(af, bf[1], (f32x4)0.f, 0, 0, 0);
      f32x4 ep2 = __builtin_amdgcn_mfma_f32_16x16x32_f16(af, bf[2], (f32x4)0.f, 0, 0, 0);
      f32x4 ep3 = __builtin_amdgcn_mfma_f32_16x16x32_f16(af, bf[3], (f32x4)0.f, 0, 0, 0);
#pragma unroll
      for (int r = 0; r < 4; ++r){
        int row = ch*16 + kq*4 + r;
        eps[row][wv*64 +  0 + li] = ep0[r];
        eps[row][wv*64 + 16 + li] = ep1[r];
        eps[row][wv*64 + 32 + li] = ep2[r];
        eps[row][wv*64 + 48 + li] = ep3[r];
      }
    }
    __syncthreads();

    // ---- phase B: walk window edges with uniform segmentation ----
    int wend = w0 + 64; if (wend > oE) wend = oE;
    for (int idx = w0; idx < wend; ++idx){
      while (idx == nextoff){
        FINALIZE(nextoff - curstart)
        curstart = nextoff;
        ++cur;
        nextoff = offs[cur + 1];
        s = 0.f; ss = 0.f;
        mx = -__builtin_huge_valf(); mn = __builtin_huge_valf();
      }
      int src = __builtin_amdgcn_readfirstlane(esrc[idx]);
      float a = (float)A_h[(size_t)src*256 + c];
      float m = eps[idx - w0][c] + a;
      s += m;
      ss = fmaf(m, m, ss);
      mx = fmaxf(mx, m);
      mn = fminf(mn, m);
    }
  }

  // tail: finalize remaining nodes (incl. zero-degree)
  while (cur < n1){
    FINALIZE(nextoff - curstart)
    curstart = nextoff;
    ++cur;
    if (cur < n1) nextoff = offs[cur + 1];
    s = 0.f; ss = 0.f;
    mx = -__builtin_huge_valf(); mn = __builtin_huge_valf();
  }
#undef FINALIZE
}

// ---------- U GEMM: LDS-free MFMA (round-8 form) ----------
__global__ __launch_bounds__(256) void k_u(const ushort* __restrict__ X2, const ushort* __restrict__ Wpk2,
                                           const float* __restrict__ sc, const float* __restrict__ Ub,
                                           float* __restrict__ uout, int Nn){
  __shared__ float su[64][68];
  int tid = threadIdx.x;
  int t   = blockIdx.y;
  int nbase = blockIdx.x*64;
  int lane = tid & 63, wv = tid >> 6;
  int li = lane & 15, kc = lane >> 4;
  int cbase = wv*48;

  f32x4 acc[4][3];
#pragma unroll
  for (int ri = 0; ri < 4; ++ri)
#pragma unroll
    for (int ci = 0; ci < 3; ++ci) acc[ri][ci] = (f32x4)0.f;

  const ushort* wb = Wpk2 + (size_t)t*192*320;

#pragma unroll 2
  for (int kt = 0; kt < 10; ++kt){
    bf16x8 ah[4], al[4], bh[3];
#pragma unroll
    for (int ri = 0; ri < 4; ++ri){
      int row = nbase + ri*16 + li;
      if (row >= Nn) row = Nn - 1;
      const ushort* ap = X2 + (((size_t)row*4 + t)*40 + kt*4 + kc)*16;
      ah[ri] = *(const bf16x8*)(ap);
      al[ri] = *(const bf16x8*)(ap + 8);
    }
#pragma unroll
    for (int ci = 0; ci < 3; ++ci){
      int col = cbase + ci*16 + li;
      bh[ci] = *(const bf16x8*)(wb + (size_t)col*320 + kt*32 + kc*8);
    }
#pragma unroll
    for (int ci = 0; ci < 3; ++ci)
#pragma unroll
      for (int ri = 0; ri < 4; ++ri){
        acc[ri][ci] = __builtin_amdgcn_mfma_f32_16x16x32_bf16(ah[ri], bh[ci], acc[ri][ci], 0, 0, 0);
        acc[ri][ci] = __builtin_amdgcn_mfma_f32_16x16x32_bf16(al[ri], bh[ci], acc[ri][ci], 0, 0, 0);
      }
  }

#define Y1_STORE(CI, OB) { _Pragma("unroll") for (int ri = 0; ri < 4; ++ri)               \
    { _Pragma("unroll") for (int r = 0; r < 4; ++r)                                        \
      su[ri*16 + kc*4 + r][(OB) + li] = acc[ri][CI][r]; } }
#define Y_ADD(CI, OB, SCOFF) { _Pragma("unroll") for (int ri = 0; ri < 4; ++ri)           \
    { _Pragma("unroll") for (int r = 0; r < 4; ++r){                                       \
      int node = ri*16 + kc*4 + r;                                                        \
      int gn = nbase + node; int gnc = (gn < Nn) ? gn : (Nn - 1);                          \
      float scl = sc[(size_t)gnc*2 + (SCOFF)];                                            \
      su[node][(OB) + li] += scl * acc[ri][CI][r]; } } }

  if (wv == 0){ Y1_STORE(0, 0)  Y1_STORE(1, 16) Y1_STORE(2, 32) }
  else if (wv == 1){ Y1_STORE(0, 48) }
  __syncthreads();
  if (wv == 1){ Y_ADD(1, 0, 0)  Y_ADD(2, 16, 0) }
  else if (wv == 2){ Y_ADD(0, 32, 0) Y_ADD(1, 48, 0) }
  __syncthreads();
  if (wv == 2){ Y_ADD(2, 0, 1) }
  else if (wv == 3){ Y_ADD(0, 16, 1) Y_ADD(1, 32, 1) Y_ADD(2, 48, 1) }
  __syncthreads();
#undef Y1_STORE
#undef Y_ADD

  for (int idx = tid; idx < 64*16; idx += 256){
    int n = idx >> 4, o4 = (idx & 15)*4;
    int gn = nbase + n;
    if (gn < Nn){
      float4 v = *(float4*)(&su[n][o4]);
      const float* ubp = Ub + t*64 + o4;
      v.x += ubp[0]; v.y += ubp[1]; v.z += ubp[2]; v.w += ubp[3];
      *(float4*)(&uout[(size_t)gn*256 + t*64 + o4]) = v;
    }
  }
}

// ---------- batchnorm stats (deterministic partials) ----------
__global__ __launch_bounds__(256) void k_bnstat(const float* __restrict__ u, float* __restrict__ part, int N){
  int c = threadIdx.x;
  int b = blockIdx.x;
  float s = 0.f, ss = 0.f;
  for (int n = b; n < N; n += gridDim.x){
    float v = u[(size_t)n*256 + c];
    s += v;
    ss = fmaf(v, v, ss);
  }
  part[(size_t)b*512 + c]       = s;
  part[(size_t)b*512 + 256 + c] = ss;
}

__global__ __launch_bounds__(256) void k_bnfin(const float* __restrict__ part, const float* __restrict__ gam,
                                               const float* __restrict__ bet, float* __restrict__ bnsc, int N){
  int c = threadIdx.x;
  float s = 0.f, ss = 0.f;
  for (int b = 0; b < BN_BLOCKS; ++b){
    s  += part[(size_t)b*512 + c];
    ss += part[(size_t)b*512 + 256 + c];
  }
  float invN = 1.f / (float)N;
  float mu  = s * invN;
  float ex2 = ss * invN;
  float var = fmaxf(ex2 - mu*mu, 0.f);
  float inv = 1.f / sqrtf(var + 1e-5f);
  float scale = gam[c] * inv;
  bnsc[c]       = scale;
  bnsc[256 + c] = bet[c] - mu*scale;
}

// ---------- X2m = bf16 hi/lo of (u*s + b), fragment-native [n][32][hi8|lo8] ----------
__global__ __launch_bounds__(256) void k_xm(const float* __restrict__ u, const float* __restrict__ bnsc,
                                            ushort* __restrict__ X2m, int N){
  for (long i = blockIdx.x*256 + threadIdx.x; i < (long)N*256; i += (long)gridDim.x*256){
    int n = (int)(i >> 8), c = (int)(i & 255);
    float v = fmaf(u[i], bnsc[c], bnsc[256 + c]);
    int j = c >> 3, pos = c & 7;
    size_t base = ((size_t)n*32 + j)*16;
    ushort hi = bf16h(v);
    X2m[base + pos]     = hi;
    X2m[base + 8 + pos] = bf16h(v - bf16f(hi));
  }
}

// ---------- mix GEMM: LDS-free MFMA + fused leaky/residual/relu ----------
__global__ __launch_bounds__(256) void k_mix(const ushort* __restrict__ X2m, const ushort* __restrict__ Wm2,
                                             const float* __restrict__ mixb, const float* __restrict__ nf,
                                             float* __restrict__ outp, int Nn){
  int tid = threadIdx.x;
  int nbase = blockIdx.x*64;
  int lane = tid & 63, wv = tid >> 6;
  int li = lane & 15, kc = lane >> 4;

  f32x4 acc[4][4];
#pragma unroll
  for (int ri = 0; ri < 4; ++ri)
#pragma unroll
    for (int ci = 0; ci < 4; ++ci) acc[ri][ci] = (f32x4)0.f;

#pragma unroll 2
  for (int kt = 0; kt < 8; ++kt){
    bf16x8 ah[4], al[4], bh[4];
#pragma unroll
    for (int ri = 0; ri < 4; ++ri){
      int row = nbase + ri*16 + li;
      if (row >= Nn) row = Nn - 1;
      const ushort* ap = X2m + (((size_t)row*32 + kt*4 + kc))*16;
      ah[ri] = *(const bf16x8*)(ap);
      al[ri] = *(const bf16x8*)(ap + 8);
    }
#pragma unroll
    for (int ci = 0; ci < 4; ++ci){
      int col = wv*64 + ci*16 + li;
      bh[ci] = *(const bf16x8*)(Wm2 + (size_t)col*256 + kt*32 + kc*8);
    }
#pragma unroll
    for (int ci = 0; ci < 4; ++ci)
#pragma unroll
      for (int ri = 0; ri < 4; ++ri){
        acc[ri][ci] = __builtin_amdgcn_mfma_f32_16x16x32_bf16(ah[ri], bh[ci], acc[ri][ci], 0, 0, 0);
        acc[ri][ci] = __builtin_amdgcn_mfma_f32_16x16x32_bf16(al[ri], bh[ci], acc[ri][ci], 0, 0, 0);
      }
  }

#pragma unroll
  for (int ri = 0; ri < 4; ++ri){
#pragma unroll
    for (int r = 0; r < 4; ++r){
      int node = ri*16 + kc*4 + r;
      int gn = nbase + node;
      if (gn < Nn){
#pragma unroll
        for (int ci = 0; ci < 4; ++ci){
          int col = wv*64 + ci*16 + li;
          float m = acc[ri][ci][r] + mixb[col];
          m = (m > 0.f) ? m : 0.01f*m;
          float o = m + nf[(size_t)gn*256 + col];
          outp[(size_t)gn*256 + col] = fmaxf(o, 0.f);
        }
      }
    }
  }
}

// ---------- host launcher ----------
extern "C" void kernel_launch(void* const* d_in, const int* in_sizes, int n_in,
                              void* d_out, int out_size, void* d_ws, size_t ws_size,
                              hipStream_t stream){
  const float* nf   = (const float*)d_in[0];
  const float* ef   = (const float*)d_in[1];
  const int*   srcv = (const int*)  d_in[2];
  const int*   dstv = (const int*)  d_in[3];
  const float* Mw   = (const float*)d_in[4];
  const float* Mb   = (const float*)d_in[5];
  const float* Uw   = (const float*)d_in[6];
  const float* Ub   = (const float*)d_in[7];
  const float* gam  = (const float*)d_in[8];
  const float* bet  = (const float*)d_in[9];
  const float* mixw = (const float*)d_in[10];
  const float* mixb = (const float*)d_in[11];
  int N = in_sizes[0] / 256;
  int E = in_sizes[2];
  float* out = (float*)d_out;

  char* wp = (char*)d_ws;
  auto alloc = [&](size_t bytes){
    char* p = wp;
    wp += (bytes + 1023) & ~(size_t)1023;
    return (void*)p;
  };
  int*      cnt   = (int*)     alloc((size_t)N*4);
  int*      offs  = (int*)     alloc((size_t)(N+1)*4);
  int*      cur   = (int*)     alloc((size_t)N*4);
  int*      bsum  = (int*)     alloc(256*4);
  int*      elist = (int*)     alloc((size_t)E*4);
  int*      esrc  = (int*)     alloc((size_t)E*4);
  // efh is dead after k_agg; X2m (written by k_xm) aliases it.
  size_t ealias   = (size_t)E*32*2;
  size_t malias   = (size_t)N*512*2;
  char*     shbuf = (char*)    alloc(ealias > malias ? ealias : malias);
  _Float16* efh   = (_Float16*)shbuf;
  ushort*   X2m   = (ushort*)  shbuf;
  _Float16* A_h   = (_Float16*)alloc((size_t)N*256*2);
  float*    B     = (float*)   alloc((size_t)N*256*4);
  float*    sc    = (float*)   alloc((size_t)N*2*4);
  float*    part  = (float*)   alloc((size_t)BN_BLOCKS*512*4);
  float*    bnsc  = (float*)   alloc(512*4);
  ushort*   X2    = (ushort*)  alloc((size_t)N*4*40*16*2);
  ushort*   Wpk2  = (ushort*)  alloc((size_t)4*192*320*2);
  ushort*   Wm2   = (ushort*)  alloc((size_t)256*256*2);
  _Float16* Wefp  = (_Float16*)alloc((size_t)16*64*8*2);

  hipMemsetAsync(cnt,  0, (size_t)N*4,  stream);
  hipMemsetAsync(cur,  0, (size_t)N*4,  stream);

  k_tU  <<<(4*192*320 + 255)/256, 256, 0, stream>>>(Uw, Wpk2);
  k_tMm <<<(256*256 + 255)/256, 256, 0, stream>>>(mixw, Wm2);
  k_tE2 <<<(16*64*8 + 255)/256, 256, 0, stream>>>(Mw, Wefp);
  k_hist<<<(E + 255)/256, 256, 0, stream>>>(dstv, cnt, E);
  k_ab  <<<2048, 256, 0, stream>>>(nf, Mw, Mb, A_h, B, N);
  k_xh  <<<2048, 256, 0, stream>>>(nf, X2, N);

  int NB = (N + 255)/256;
  k_scan1<<<NB, 256, 0, stream>>>(cnt, offs, bsum, N);
  k_scan2<<<1, 256, 0, stream>>>(bsum, NB);
  k_scan3<<<NB, 256, 0, stream>>>(offs, bsum, N, E);
  k_fill <<<(E + 255)/256, 256, 0, stream>>>(dstv, offs, cur, elist, E);
  k_perm <<<(E*8 + 255)/256, 256, 0, stream>>>(elist, srcv, ef, esrc, efh, E);

  k_agg<<<(N + NPB - 1)/NPB, 256, 0, stream>>>(offs, esrc, efh, A_h, B, Wefp, X2, sc, N, E);

  dim3 ugrid((N + 63)/64, 4);
  k_u<<<ugrid, 256, 0, stream>>>(X2, Wpk2, sc, Ub, out, N);

  k_bnstat<<<BN_BLOCKS, 256, 0, stream>>>(out, part, N);
  k_bnfin <<<1, 256, 0, stream>>>(part, gam, bet, bnsc, N);
  k_xm   <<<2048, 256, 0, stream>>>(out, bnsc, X2m, N);
  k_mix  <<<(N + 63)/64, 256, 0, stream>>>(X2m, Wm2, mixb, nf, out, N);
}

// Round 12
// 502.872 us; speedup vs baseline: 1.5113x; 1.5113x over previous
//
#include <hip/hip_runtime.h>
#include <math.h>

constexpr float DELTA_ = 2.5f;
#define BN_BLOCKS 512
#define NPB 8   // nodes per k_agg block

typedef __attribute__((ext_vector_type(8))) short bf16x8;
typedef __attribute__((ext_vector_type(8))) _Float16 f16x8;
typedef __attribute__((ext_vector_type(4))) float f32x4;

__device__ inline ushort bf16h(float x){
  union { float f; unsigned u; } v; v.f = x;
  unsigned r = v.u + 0x7fffu + ((v.u >> 16) & 1u);
  return (ushort)(r >> 16);
}
__device__ inline float bf16f(ushort h){
  union { unsigned u; float f; } v; v.u = ((unsigned)h) << 16;
  return v.f;
}

// ---------- U-weights: Wpk2[t][192][320] bf16 (col = path*64+o; path1/2 zero h-rows) ----------
__global__ __launch_bounds__(256) void k_tU(const float* __restrict__ Uw, ushort* __restrict__ Wpk2){
  int i = blockIdx.x*256 + threadIdx.x;          // i = (t*192+col)*320 + k
  if (i >= 4*192*320) return;
  int k   = i % 320;
  int col = (i/320) % 192;
  int t   = i/(320*192);
  int path = col >> 6, o = col & 63;
  float v = 0.f;
  int src = -1;
  if (k < 64){ if (path == 0) src = k; }
  else        src = k + path*256;
  if (src >= 0) v = Uw[((size_t)(t*64 + o))*832 + src];
  Wpk2[i] = bf16h(v);
}

// ---------- mix weights: Wm2[col][256] bf16 ----------
__global__ __launch_bounds__(256) void k_tMm(const float* __restrict__ mixw, ushort* __restrict__ Wm2){
  int i = blockIdx.x*256 + threadIdx.x;
  if (i >= 256*256) return;
  Wm2[i] = bf16h(mixw[i]);
}

// ---------- W_ef in B-fragment layout: Wefp[(cb*64+lane)*8+j], ch=cb*16+(lane&15), k=(lane>>4)*8+j ----------
__global__ __launch_bounds__(256) void k_tE2(const float* __restrict__ Mw, _Float16* __restrict__ Wefp){
  int i = blockIdx.x*256 + threadIdx.x;
  if (i >= 16*64*8) return;
  int j    = i & 7;
  int lane = (i >> 3) & 63;
  int cb   = i >> 9;
  int ch = cb*16 + (lane & 15);
  int k  = ((lane >> 4) & 3)*8 + j;
  Wefp[i] = (_Float16)Mw[(size_t)ch*160 + 128 + k];
}

// ---------- X2 h-part: X2[n][t][j][hi8|lo8] for k=0..63 ----------
__global__ __launch_bounds__(256) void k_xh(const float* __restrict__ nf, ushort* __restrict__ X2, int N){
  for (long i = blockIdx.x*256 + threadIdx.x; i < (long)N*256; i += (long)gridDim.x*256){
    int n = (int)(i >> 8), c = (int)(i & 255);
    int t = c >> 6, d = c & 63;
    int j = d >> 3, pos = d & 7;
    float v = nf[i];
    ushort hi = bf16h(v);
    size_t base = (((size_t)n*4 + t)*40 + j)*16;
    X2[base + pos]     = hi;
    X2[base + 8 + pos] = bf16h(v - bf16f(hi));
  }
}

__global__ __launch_bounds__(256) void k_hist(const int* __restrict__ dstv, int* __restrict__ cnt, int E){
  int e = blockIdx.x*256 + threadIdx.x;
  if (e < E) atomicAdd(&cnt[dstv[e]], 1);
}

__global__ __launch_bounds__(256) void k_scan1(const int* __restrict__ cnt, int* __restrict__ offs,
                                               int* __restrict__ bsum, int N){
  __shared__ int lds[256];
  int i = threadIdx.x;
  int g = blockIdx.x*256 + i;
  int v = (g < N) ? cnt[g] : 0;
  int acc = v;
  lds[i] = acc; __syncthreads();
  for (int s = 1; s < 256; s <<= 1){
    int t = (i >= s) ? lds[i - s] : 0;
    __syncthreads();
    acc += t; lds[i] = acc;
    __syncthreads();
  }
  if (g < N) offs[g] = acc - v;
  if (i == 255) bsum[blockIdx.x] = acc;
}

__global__ __launch_bounds__(256) void k_scan2(int* __restrict__ bsum, int NB){
  __shared__ int lds[256];
  int i = threadIdx.x;
  int v = (i < NB) ? bsum[i] : 0;
  int acc = v;
  lds[i] = acc; __syncthreads();
  for (int s = 1; s < 256; s <<= 1){
    int t = (i >= s) ? lds[i - s] : 0;
    __syncthreads();
    acc += t; lds[i] = acc;
    __syncthreads();
  }
  if (i < NB) bsum[i] = acc - v;
}

__global__ __launch_bounds__(256) void k_scan3(int* __restrict__ offs, const int* __restrict__ bsum, int N, int E){
  int g = blockIdx.x*256 + threadIdx.x;
  if (g < N) offs[g] += bsum[blockIdx.x];
  if (g == 0) offs[N] = E;
}

__global__ __launch_bounds__(256) void k_fill(const int* __restrict__ dstv, const int* __restrict__ offs,
                                              int* __restrict__ cur, int* __restrict__ elist, int E){
  int e = blockIdx.x*256 + threadIdx.x;
  if (e < E){
    int d = dstv[e];
    elist[offs[d] + atomicAdd(&cur[d], 1)] = e;
  }
}

// ---------- permute srcv + edge features (f16) into CSR order ----------
__global__ __launch_bounds__(256) void k_perm(const int* __restrict__ elist, const int* __restrict__ srcv,
                                              const float* __restrict__ efeat,
                                              int* __restrict__ esrc, _Float16* __restrict__ efh, int E){
  int g = blockIdx.x*256 + threadIdx.x;
  int pos = g >> 3;
  int q   = g & 7;
  if (pos >= E) return;
  int e = elist[pos];
  if (q == 0) esrc[pos] = srcv[e];
  float4 v = *(const float4*)(efeat + (size_t)e*32 + q*4);
  union { ushort4 u; _Float16 h[4]; } cv;
  cv.h[0] = (_Float16)v.x; cv.h[1] = (_Float16)v.y;
  cv.h[2] = (_Float16)v.z; cv.h[3] = (_Float16)v.w;
  *(ushort4*)(efh + (size_t)pos*32 + q*4) = cv.u;
}

// ---------- A_h = f16(W_src*h), B = W_dst*h + M_b ----------
__global__ __launch_bounds__(256) void k_ab(const float* __restrict__ nf, const float* __restrict__ Mw,
                                            const float* __restrict__ Mb,
                                            _Float16* __restrict__ A_h, float* __restrict__ B, int N){
  int c = threadIdx.x;
  int t = __builtin_amdgcn_readfirstlane(threadIdx.x >> 6);
  float ws[64], wd[64];
  const float* row = Mw + (size_t)c*160;
#pragma unroll
  for (int k = 0; k < 64; k += 4){
    float4 a = *(const float4*)(row + k);
    float4 b = *(const float4*)(row + 64 + k);
    ws[k]=a.x; ws[k+1]=a.y; ws[k+2]=a.z; ws[k+3]=a.w;
    wd[k]=b.x; wd[k+1]=b.y; wd[k+2]=b.z; wd[k+3]=b.w;
  }
  float bias = Mb[c];
  for (int n = blockIdx.x; n < N; n += gridDim.x){
    const float* h = nf + (size_t)n*256 + t*64;
    float sa = 0.f, sb = 0.f;
#pragma unroll
    for (int k = 0; k < 64; k += 4){
      float4 h4 = *(const float4*)(h + k);
      sa = fmaf(ws[k], h4.x, sa);  sb = fmaf(wd[k], h4.x, sb);
      sa = fmaf(ws[k+1], h4.y, sa); sb = fmaf(wd[k+1], h4.y, sb);
      sa = fmaf(ws[k+2], h4.z, sa); sb = fmaf(wd[k+2], h4.z, sb);
      sa = fmaf(ws[k+3], h4.w, sa); sb = fmaf(wd[k+3], h4.w, sb);
    }
    A_h[(size_t)n*256 + c] = (_Float16)sa;
    B[(size_t)n*256 + c] = sb + bias;
  }
}

// ---------- aggregation v3: two-phase MFMA + batched gather fold-in ----------
// Phase A  (per 64-edge window): waves MFMA eproj into f16 LDS (33.8 KB -> 4 blocks/CU).
// Phase A2 : unroll-8 batched A_h gathers (no dependent chain) folded into eps in place
//            (thread owns column c exclusively -> race-free).
// Phase B  : serial walk reads finished message from LDS; FINALIZE logic r11-validated.
__global__ __launch_bounds__(256) void k_agg(const int* __restrict__ offs, const int* __restrict__ esrc,
                                             const _Float16* __restrict__ efh,
                                             const _Float16* __restrict__ A_h, const float* __restrict__ B,
                                             const _Float16* __restrict__ Wefp,
                                             ushort* __restrict__ X2, float* __restrict__ sc, int N, int E){
  __shared__ _Float16 eps[64][264];
  int tid = threadIdx.x;
  int lane = tid & 63, wv = tid >> 6;
  int li = lane & 15, kq = lane >> 4;
  int c = tid;                                  // this thread's channel
  int tw = c >> 6, d = c & 63;                  // tower, within-tower channel

  int n0 = blockIdx.x * NPB;
  if (n0 >= N) return;
  int n1 = n0 + NPB; if (n1 > N) n1 = N;
  int oS = offs[n0], oE = offs[n1];

  f16x8 bf[4];
#pragma unroll
  for (int cbl = 0; cbl < 4; ++cbl)
    bf[cbl] = *(const f16x8*)(Wefp + ((size_t)(wv*4 + cbl)*64 + lane)*8);

  int cur = n0;
  int curstart = oS;
  int nextoff = offs[n0 + 1];
  float s = 0.f, ss = 0.f;
  float mx = -__builtin_huge_valf(), mn = __builtin_huge_valf();

#define FINALIZE(CNT)                                                             \
  {                                                                                \
    float b = B[(size_t)cur*256 + c];                                              \
    float deg = (float)(CNT);                                                      \
    float degc = fmaxf(deg, 1.f);                                                  \
    float inv = 1.f / degc;                                                        \
    float S  = fmaf(deg, b, s);                                                    \
    float SS = fmaf(deg, b*b, fmaf(2.f*b, s, ss));                                 \
    float mean = S * inv;                                                          \
    float var  = fmaxf(SS * inv - mean*mean, 0.f);                                 \
    float sd   = sqrtf(var + 1e-30f);                                              \
    float MX = ((CNT) > 0) ? (b + mx) : 0.f;                                       \
    float MN = ((CNT) > 0) ? (b + mn) : 0.f;                                       \
    size_t xb = (((size_t)cur*4 + tw)*40)*16;                                      \
    { int kk = 64 + d;       ushort h2 = bf16h(mean);                              \
      X2[xb + (kk>>3)*16 + (kk&7)] = h2;                                           \
      X2[xb + (kk>>3)*16 + 8 + (kk&7)] = bf16h(mean - bf16f(h2)); }                \
    { int kk = 128 + d;      ushort h2 = bf16h(MX);                                \
      X2[xb + (kk>>3)*16 + (kk&7)] = h2;                                           \
      X2[xb + (kk>>3)*16 + 8 + (kk&7)] = bf16h(MX - bf16f(h2)); }                  \
    { int kk = 192 + d;      ushort h2 = bf16h(MN);                                \
      X2[xb + (kk>>3)*16 + (kk&7)] = h2;                                           \
      X2[xb + (kk>>3)*16 + 8 + (kk&7)] = bf16h(MN - bf16f(h2)); }                  \
    { int kk = 256 + d;      ushort h2 = bf16h(sd);                                \
      X2[xb + (kk>>3)*16 + (kk&7)] = h2;                                           \
      X2[xb + (kk>>3)*16 + 8 + (kk&7)] = bf16h(sd - bf16f(h2)); }                  \
    if (tid == 0){                                                                 \
      float logd = logf(deg + 1.f);                                                \
      sc[(size_t)cur*2]     = logd * (1.f / DELTA_);                               \
      sc[(size_t)cur*2 + 1] = ((CNT) > 0) ? (DELTA_ / fmaxf(logd, 1e-12f)) : 0.f;  \
    }                                                                              \
  }

  for (int w0 = oS; w0 < oE; w0 += 64){
    // ---- phase A: eproj for edges [w0, w0+64) into f16 LDS ----
    __syncthreads();
#pragma unroll
    for (int ch = 0; ch < 4; ++ch){
      int pos = w0 + ch*16 + li;
      if (pos > E - 1) pos = E - 1;
      f16x8 af = *(const f16x8*)(efh + (size_t)pos*32 + kq*8);
      f32x4 ep0 = __builtin_amdgcn_mfma_f32_16x16x32_f16(af, bf[0], (f32x4)0.f, 0, 0, 0);
      f32x4 ep1 = __builtin_amdgcn_mfma_f32_16x16x32_f16(af, bf[1], (f32x4)0.f, 0, 0, 0);
      f32x4 ep2 = __builtin_amdgcn_mfma_f32_16x16x32_f16(af, bf[2], (f32x4)0.f, 0, 0, 0);
      f32x4 ep3 = __builtin_amdgcn_mfma_f32_16x16x32_f16(af, bf[3], (f32x4)0.f, 0, 0, 0);
#pragma unroll
      for (int r = 0; r < 4; ++r){
        int row = ch*16 + kq*4 + r;
        eps[row][wv*64 +  0 + li] = (_Float16)ep0[r];
        eps[row][wv*64 + 16 + li] = (_Float16)ep1[r];
        eps[row][wv*64 + 32 + li] = (_Float16)ep2[r];
        eps[row][wv*64 + 48 + li] = (_Float16)ep3[r];
      }
    }
    __syncthreads();

    // ---- phase A2: batched A-gathers folded into eps (thread owns col c) ----
#pragma unroll 8
    for (int q = 0; q < 64; ++q){
      int idx = w0 + q; if (idx > oE - 1) idx = oE - 1;
      int src = esrc[idx];                        // wave-uniform -> s_load
      float av = (float)A_h[(size_t)src*256 + c];
      eps[q][c] = (_Float16)((float)eps[q][c] + av);
    }
    __syncthreads();

    // ---- phase B: walk window edges with uniform segmentation (LDS-only) ----
    int wend = w0 + 64; if (wend > oE) wend = oE;
    for (int idx = w0; idx < wend; ++idx){
      while (idx == nextoff){
        FINALIZE(nextoff - curstart)
        curstart = nextoff;
        ++cur;
        nextoff = offs[cur + 1];
        s = 0.f; ss = 0.f;
        mx = -__builtin_huge_valf(); mn = __builtin_huge_valf();
      }
      float m = (float)eps[idx - w0][c];
      s += m;
      ss = fmaf(m, m, ss);
      mx = fmaxf(mx, m);
      mn = fminf(mn, m);
    }
  }

  // tail: finalize remaining nodes (incl. zero-degree)
  while (cur < n1){
    FINALIZE(nextoff - curstart)
    curstart = nextoff;
    ++cur;
    if (cur < n1) nextoff = offs[cur + 1];
    s = 0.f; ss = 0.f;
    mx = -__builtin_huge_valf(); mn = __builtin_huge_valf();
  }
#undef FINALIZE
}

// ---------- U GEMM: LDS-free MFMA (round-8 form) ----------
__global__ __launch_bounds__(256) void k_u(const ushort* __restrict__ X2, const ushort* __restrict__ Wpk2,
                                           const float* __restrict__ sc, const float* __restrict__ Ub,
                                           float* __restrict__ uout, int Nn){
  __shared__ float su[64][68];
  int tid = threadIdx.x;
  int t   = blockIdx.y;
  int nbase = blockIdx.x*64;
  int lane = tid & 63, wv = tid >> 6;
  int li = lane & 15, kc = lane >> 4;
  int cbase = wv*48;

  f32x4 acc[4][3];
#pragma unroll
  for (int ri = 0; ri < 4; ++ri)
#pragma unroll
    for (int ci = 0; ci < 3; ++ci) acc[ri][ci] = (f32x4)0.f;

  const ushort* wb = Wpk2 + (size_t)t*192*320;

#pragma unroll 2
  for (int kt = 0; kt < 10; ++kt){
    bf16x8 ah[4], al[4], bh[3];
#pragma unroll
    for (int ri = 0; ri < 4; ++ri){
      int row = nbase + ri*16 + li;
      if (row >= Nn) row = Nn - 1;
      const ushort* ap = X2 + (((size_t)row*4 + t)*40 + kt*4 + kc)*16;
      ah[ri] = *(const bf16x8*)(ap);
      al[ri] = *(const bf16x8*)(ap + 8);
    }
#pragma unroll
    for (int ci = 0; ci < 3; ++ci){
      int col = cbase + ci*16 + li;
      bh[ci] = *(const bf16x8*)(wb + (size_t)col*320 + kt*32 + kc*8);
    }
#pragma unroll
    for (int ci = 0; ci < 3; ++ci)
#pragma unroll
      for (int ri = 0; ri < 4; ++ri){
        acc[ri][ci] = __builtin_amdgcn_mfma_f32_16x16x32_bf16(ah[ri], bh[ci], acc[ri][ci], 0, 0, 0);
        acc[ri][ci] = __builtin_amdgcn_mfma_f32_16x16x32_bf16(al[ri], bh[ci], acc[ri][ci], 0, 0, 0);
      }
  }

#define Y1_STORE(CI, OB) { _Pragma("unroll") for (int ri = 0; ri < 4; ++ri)               \
    { _Pragma("unroll") for (int r = 0; r < 4; ++r)                                        \
      su[ri*16 + kc*4 + r][(OB) + li] = acc[ri][CI][r]; } }
#define Y_ADD(CI, OB, SCOFF) { _Pragma("unroll") for (int ri = 0; ri < 4; ++ri)           \
    { _Pragma("unroll") for (int r = 0; r < 4; ++r){                                       \
      int node = ri*16 + kc*4 + r;                                                        \
      int gn = nbase + node; int gnc = (gn < Nn) ? gn : (Nn - 1);                          \
      float scl = sc[(size_t)gnc*2 + (SCOFF)];                                            \
      su[node][(OB) + li] += scl * acc[ri][CI][r]; } } }

  if (wv == 0){ Y1_STORE(0, 0)  Y1_STORE(1, 16) Y1_STORE(2, 32) }
  else if (wv == 1){ Y1_STORE(0, 48) }
  __syncthreads();
  if (wv == 1){ Y_ADD(1, 0, 0)  Y_ADD(2, 16, 0) }
  else if (wv == 2){ Y_ADD(0, 32, 0) Y_ADD(1, 48, 0) }
  __syncthreads();
  if (wv == 2){ Y_ADD(2, 0, 1) }
  else if (wv == 3){ Y_ADD(0, 16, 1) Y_ADD(1, 32, 1) Y_ADD(2, 48, 1) }
  __syncthreads();
#undef Y1_STORE
#undef Y_ADD

  for (int idx = tid; idx < 64*16; idx += 256){
    int n = idx >> 4, o4 = (idx & 15)*4;
    int gn = nbase + n;
    if (gn < Nn){
      float4 v = *(float4*)(&su[n][o4]);
      const float* ubp = Ub + t*64 + o4;
      v.x += ubp[0]; v.y += ubp[1]; v.z += ubp[2]; v.w += ubp[3];
      *(float4*)(&uout[(size_t)gn*256 + t*64 + o4]) = v;
    }
  }
}

// ---------- batchnorm stats (deterministic partials) ----------
__global__ __launch_bounds__(256) void k_bnstat(const float* __restrict__ u, float* __restrict__ part, int N){
  int c = threadIdx.x;
  int b = blockIdx.x;
  float s = 0.f, ss = 0.f;
  for (int n = b; n < N; n += gridDim.x){
    float v = u[(size_t)n*256 + c];
    s += v;
    ss = fmaf(v, v, ss);
  }
  part[(size_t)b*512 + c]       = s;
  part[(size_t)b*512 + 256 + c] = ss;
}

__global__ __launch_bounds__(256) void k_bnfin(const float* __restrict__ part, const float* __restrict__ gam,
                                               const float* __restrict__ bet, float* __restrict__ bnsc, int N){
  int c = threadIdx.x;
  float s = 0.f, ss = 0.f;
  for (int b = 0; b < BN_BLOCKS; ++b){
    s  += part[(size_t)b*512 + c];
    ss += part[(size_t)b*512 + 256 + c];
  }
  float invN = 1.f / (float)N;
  float mu  = s * invN;
  float ex2 = ss * invN;
  float var = fmaxf(ex2 - mu*mu, 0.f);
  float inv = 1.f / sqrtf(var + 1e-5f);
  float scale = gam[c] * inv;
  bnsc[c]       = scale;
  bnsc[256 + c] = bet[c] - mu*scale;
}

// ---------- X2m = bf16 hi/lo of (u*s + b), fragment-native [n][32][hi8|lo8] ----------
__global__ __launch_bounds__(256) void k_xm(const float* __restrict__ u, const float* __restrict__ bnsc,
                                            ushort* __restrict__ X2m, int N){
  for (long i = blockIdx.x*256 + threadIdx.x; i < (long)N*256; i += (long)gridDim.x*256){
    int n = (int)(i >> 8), c = (int)(i & 255);
    float v = fmaf(u[i], bnsc[c], bnsc[256 + c]);
    int j = c >> 3, pos = c & 7;
    size_t base = ((size_t)n*32 + j)*16;
    ushort hi = bf16h(v);
    X2m[base + pos]     = hi;
    X2m[base + 8 + pos] = bf16h(v - bf16f(hi));
  }
}

// ---------- mix GEMM: LDS-free MFMA + fused leaky/residual/relu ----------
__global__ __launch_bounds__(256) void k_mix(const ushort* __restrict__ X2m, const ushort* __restrict__ Wm2,
                                             const float* __restrict__ mixb, const float* __restrict__ nf,
                                             float* __restrict__ outp, int Nn){
  int tid = threadIdx.x;
  int nbase = blockIdx.x*64;
  int lane = tid & 63, wv = tid >> 6;
  int li = lane & 15, kc = lane >> 4;

  f32x4 acc[4][4];
#pragma unroll
  for (int ri = 0; ri < 4; ++ri)
#pragma unroll
    for (int ci = 0; ci < 4; ++ci) acc[ri][ci] = (f32x4)0.f;

#pragma unroll 2
  for (int kt = 0; kt < 8; ++kt){
    bf16x8 ah[4], al[4], bh[4];
#pragma unroll
    for (int ri = 0; ri < 4; ++ri){
      int row = nbase + ri*16 + li;
      if (row >= Nn) row = Nn - 1;
      const ushort* ap = X2m + (((size_t)row*32 + kt*4 + kc))*16;
      ah[ri] = *(const bf16x8*)(ap);
      al[ri] = *(const bf16x8*)(ap + 8);
    }
#pragma unroll
    for (int ci = 0; ci < 4; ++ci){
      int col = wv*64 + ci*16 + li;
      bh[ci] = *(const bf16x8*)(Wm2 + (size_t)col*256 + kt*32 + kc*8);
    }
#pragma unroll
    for (int ci = 0; ci < 4; ++ci)
#pragma unroll
      for (int ri = 0; ri < 4; ++ri){
        acc[ri][ci] = __builtin_amdgcn_mfma_f32_16x16x32_bf16(ah[ri], bh[ci], acc[ri][ci], 0, 0, 0);
        acc[ri][ci] = __builtin_amdgcn_mfma_f32_16x16x32_bf16(al[ri], bh[ci], acc[ri][ci], 0, 0, 0);
      }
  }

#pragma unroll
  for (int ri = 0; ri < 4; ++ri){
#pragma unroll
    for (int r = 0; r < 4; ++r){
      int node = ri*16 + kc*4 + r;
      int gn = nbase + node;
      if (gn < Nn){
#pragma unroll
        for (int ci = 0; ci < 4; ++ci){
          int col = wv*64 + ci*16 + li;
          float m = acc[ri][ci][r] + mixb[col];
          m = (m > 0.f) ? m : 0.01f*m;
          float o = m + nf[(size_t)gn*256 + col];
          outp[(size_t)gn*256 + col] = fmaxf(o, 0.f);
        }
      }
    }
  }
}

// ---------- host launcher ----------
extern "C" void kernel_launch(void* const* d_in, const int* in_sizes, int n_in,
                              void* d_out, int out_size, void* d_ws, size_t ws_size,
                              hipStream_t stream){
  const float* nf   = (const float*)d_in[0];
  const float* ef   = (const float*)d_in[1];
  const int*   srcv = (const int*)  d_in[2];
  const int*   dstv = (const int*)  d_in[3];
  const float* Mw   = (const float*)d_in[4];
  const float* Mb   = (const float*)d_in[5];
  const float* Uw   = (const float*)d_in[6];
  const float* Ub   = (const float*)d_in[7];
  const float* gam  = (const float*)d_in[8];
  const float* bet  = (const float*)d_in[9];
  const float* mixw = (const float*)d_in[10];
  const float* mixb = (const float*)d_in[11];
  int N = in_sizes[0] / 256;
  int E = in_sizes[2];
  float* out = (float*)d_out;

  char* wp = (char*)d_ws;
  auto alloc = [&](size_t bytes){
    char* p = wp;
    wp += (bytes + 1023) & ~(size_t)1023;
    return (void*)p;
  };
  int*      cnt   = (int*)     alloc((size_t)N*4);
  int*      offs  = (int*)     alloc((size_t)(N+1)*4);
  int*      cur   = (int*)     alloc((size_t)N*4);
  int*      bsum  = (int*)     alloc(256*4);
  int*      elist = (int*)     alloc((size_t)E*4);
  int*      esrc  = (int*)     alloc((size_t)E*4);
  // efh is dead after k_agg; X2m (written by k_xm) aliases it.
  size_t ealias   = (size_t)E*32*2;
  size_t malias   = (size_t)N*512*2;
  char*     shbuf = (char*)    alloc(ealias > malias ? ealias : malias);
  _Float16* efh   = (_Float16*)shbuf;
  ushort*   X2m   = (ushort*)  shbuf;
  _Float16* A_h   = (_Float16*)alloc((size_t)N*256*2);
  float*    B     = (float*)   alloc((size_t)N*256*4);
  float*    sc    = (float*)   alloc((size_t)N*2*4);
  float*    part  = (float*)   alloc((size_t)BN_BLOCKS*512*4);
  float*    bnsc  = (float*)   alloc(512*4);
  ushort*   X2    = (ushort*)  alloc((size_t)N*4*40*16*2);
  ushort*   Wpk2  = (ushort*)  alloc((size_t)4*192*320*2);
  ushort*   Wm2   = (ushort*)  alloc((size_t)256*256*2);
  _Float16* Wefp  = (_Float16*)alloc((size_t)16*64*8*2);

  hipMemsetAsync(cnt,  0, (size_t)N*4,  stream);
  hipMemsetAsync(cur,  0, (size_t)N*4,  stream);

  k_tU  <<<(4*192*320 + 255)/256, 256, 0, stream>>>(Uw, Wpk2);
  k_tMm <<<(256*256 + 255)/256, 256, 0, stream>>>(mixw, Wm2);
  k_tE2 <<<(16*64*8 + 255)/256, 256, 0, stream>>>(Mw, Wefp);
  k_hist<<<(E + 255)/256, 256, 0, stream>>>(dstv, cnt, E);
  k_ab  <<<2048, 256, 0, stream>>>(nf, Mw, Mb, A_h, B, N);
  k_xh  <<<2048, 256, 0, stream>>>(nf, X2, N);

  int NB = (N + 255)/256;
  k_scan1<<<NB, 256, 0, stream>>>(cnt, offs, bsum, N);
  k_scan2<<<1, 256, 0, stream>>>(bsum, NB);
  k_scan3<<<NB, 256, 0, stream>>>(offs, bsum, N, E);
  k_fill <<<(E + 255)/256, 256, 0, stream>>>(dstv, offs, cur, elist, E);
  k_perm <<<(E*8 + 255)/256, 256, 0, stream>>>(elist, srcv, ef, esrc, efh, E);

  k_agg<<<(N + NPB - 1)/NPB, 256, 0, stream>>>(offs, esrc, efh, A_h, B, Wefp, X2, sc, N, E);

  dim3 ugrid((N + 63)/64, 4);
  k_u<<<ugrid, 256, 0, stream>>>(X2, Wpk2, sc, Ub, out, N);

  k_bnstat<<<BN_BLOCKS, 256, 0, stream>>>(out, part, N);
  k_bnfin <<<1, 256, 0, stream>>>(part, gam, bet, bnsc, N);
  k_xm   <<<2048, 256, 0, stream>>>(out, bnsc, X2m, N);
  k_mix  <<<(N + 63)/64, 256, 0, stream>>>(X2m, Wm2, mixb, nf, out, N);
}

// Round 13
// 453.640 us; speedup vs baseline: 1.6753x; 1.1085x over previous
//
#include <hip/hip_runtime.h>
#include <math.h>

constexpr float DELTA_ = 2.5f;
#define BN_BLOCKS 512
#define NPB 8   // nodes per k_agg block

typedef __attribute__((ext_vector_type(8))) short bf16x8;
typedef __attribute__((ext_vector_type(8))) _Float16 f16x8;
typedef __attribute__((ext_vector_type(4))) float f32x4;

__device__ inline ushort bf16h(float x){
  union { float f; unsigned u; } v; v.f = x;
  unsigned r = v.u + 0x7fffu + ((v.u >> 16) & 1u);
  return (ushort)(r >> 16);
}
__device__ inline float bf16f(ushort h){
  union { unsigned u; float f; } v; v.u = ((unsigned)h) << 16;
  return v.f;
}

// ---------- U-weights: Wpk2[t][192][320] bf16 (col = path*64+o; path1/2 zero h-rows) ----------
__global__ __launch_bounds__(256) void k_tU(const float* __restrict__ Uw, ushort* __restrict__ Wpk2){
  int i = blockIdx.x*256 + threadIdx.x;          // i = (t*192+col)*320 + k
  if (i >= 4*192*320) return;
  int k   = i % 320;
  int col = (i/320) % 192;
  int t   = i/(320*192);
  int path = col >> 6, o = col & 63;
  float v = 0.f;
  int src = -1;
  if (k < 64){ if (path == 0) src = k; }
  else        src = k + path*256;
  if (src >= 0) v = Uw[((size_t)(t*64 + o))*832 + src];
  Wpk2[i] = bf16h(v);
}

// ---------- mix weights: Wm2[col][256] bf16 ----------
__global__ __launch_bounds__(256) void k_tMm(const float* __restrict__ mixw, ushort* __restrict__ Wm2){
  int i = blockIdx.x*256 + threadIdx.x;
  if (i >= 256*256) return;
  Wm2[i] = bf16h(mixw[i]);
}

// ---------- M-weights (W_src | W_ef) in B-fragment layout, K=96 ----------
// Wall[t][cb][slice][lane][8]: ch = t*64 + cb*16 + (lane&15), k = slice*32 + (lane>>4)*8 + j;
// k<64 -> Mw[ch][k] (W_src); k>=64 -> Mw[ch][128 + (k-64)] (W_ef).
__global__ __launch_bounds__(256) void k_tW(const float* __restrict__ Mw, _Float16* __restrict__ Wall){
  int i = blockIdx.x*256 + threadIdx.x;
  if (i >= 4*4*3*64*8) return;
  int j     = i & 7;
  int lane  = (i >> 3) & 63;
  int slice = (i / 512) % 3;
  int cb    = (i / 1536) % 4;
  int t     = i / 6144;
  int ch = t*64 + cb*16 + (lane & 15);
  int k  = slice*32 + ((lane >> 4) & 3)*8 + j;
  int off = (k < 64) ? k : (128 + (k - 64));
  Wall[i] = (_Float16)Mw[(size_t)ch*160 + off];
}

// ---------- X2 h-part: X2[n][t][j][hi8|lo8] for k=0..63 ----------
__global__ __launch_bounds__(256) void k_xh(const float* __restrict__ nf, ushort* __restrict__ X2, int N){
  for (long i = blockIdx.x*256 + threadIdx.x; i < (long)N*256; i += (long)gridDim.x*256){
    int n = (int)(i >> 8), c = (int)(i & 255);
    int t = c >> 6, d = c & 63;
    int j = d >> 3, pos = d & 7;
    float v = nf[i];
    ushort hi = bf16h(v);
    size_t base = (((size_t)n*4 + t)*40 + j)*16;
    X2[base + pos]     = hi;
    X2[base + 8 + pos] = bf16h(v - bf16f(hi));
  }
}

__global__ __launch_bounds__(256) void k_hist(const int* __restrict__ dstv, int* __restrict__ cnt, int E){
  int e = blockIdx.x*256 + threadIdx.x;
  if (e < E) atomicAdd(&cnt[dstv[e]], 1);
}

__global__ __launch_bounds__(256) void k_scan1(const int* __restrict__ cnt, int* __restrict__ offs,
                                               int* __restrict__ bsum, int N){
  __shared__ int lds[256];
  int i = threadIdx.x;
  int g = blockIdx.x*256 + i;
  int v = (g < N) ? cnt[g] : 0;
  int acc = v;
  lds[i] = acc; __syncthreads();
  for (int s = 1; s < 256; s <<= 1){
    int t = (i >= s) ? lds[i - s] : 0;
    __syncthreads();
    acc += t; lds[i] = acc;
    __syncthreads();
  }
  if (g < N) offs[g] = acc - v;
  if (i == 255) bsum[blockIdx.x] = acc;
}

__global__ __launch_bounds__(256) void k_scan2(int* __restrict__ bsum, int NB){
  __shared__ int lds[256];
  int i = threadIdx.x;
  int v = (i < NB) ? bsum[i] : 0;
  int acc = v;
  lds[i] = acc; __syncthreads();
  for (int s = 1; s < 256; s <<= 1){
    int t = (i >= s) ? lds[i - s] : 0;
    __syncthreads();
    acc += t; lds[i] = acc;
    __syncthreads();
  }
  if (i < NB) bsum[i] = acc - v;
}

__global__ __launch_bounds__(256) void k_scan3(int* __restrict__ offs, const int* __restrict__ bsum, int N, int E){
  int g = blockIdx.x*256 + threadIdx.x;
  if (g < N) offs[g] += bsum[blockIdx.x];
  if (g == 0) offs[N] = E;
}

__global__ __launch_bounds__(256) void k_fill(const int* __restrict__ dstv, const int* __restrict__ offs,
                                              int* __restrict__ cur, int* __restrict__ elist, int E){
  int e = blockIdx.x*256 + threadIdx.x;
  if (e < E){
    int d = dstv[e];
    elist[offs[d] + atomicAdd(&cur[d], 1)] = e;
  }
}

// ---------- permute srcv + edge features (f16) into CSR order ----------
__global__ __launch_bounds__(256) void k_perm(const int* __restrict__ elist, const int* __restrict__ srcv,
                                              const float* __restrict__ efeat,
                                              int* __restrict__ esrc, _Float16* __restrict__ efh, int E){
  int g = blockIdx.x*256 + threadIdx.x;
  int pos = g >> 3;
  int q   = g & 7;
  if (pos >= E) return;
  int e = elist[pos];
  if (q == 0) esrc[pos] = srcv[e];
  float4 v = *(const float4*)(efeat + (size_t)e*32 + q*4);
  union { ushort4 u; _Float16 h[4]; } cv;
  cv.h[0] = (_Float16)v.x; cv.h[1] = (_Float16)v.y;
  cv.h[2] = (_Float16)v.z; cv.h[3] = (_Float16)v.w;
  *(ushort4*)(efh + (size_t)pos*32 + q*4) = cv.u;
}

// ---------- nfh = f16(nf), B = W_dst*h + M_b ----------
__global__ __launch_bounds__(256) void k_ab(const float* __restrict__ nf, const float* __restrict__ Mw,
                                            const float* __restrict__ Mb,
                                            _Float16* __restrict__ nfh, float* __restrict__ B, int N){
  int c = threadIdx.x;
  int t = __builtin_amdgcn_readfirstlane(threadIdx.x >> 6);
  float wd[64];
  const float* row = Mw + (size_t)c*160 + 64;
#pragma unroll
  for (int k = 0; k < 64; k += 4){
    float4 b = *(const float4*)(row + k);
    wd[k]=b.x; wd[k+1]=b.y; wd[k+2]=b.z; wd[k+3]=b.w;
  }
  float bias = Mb[c];
  for (int n = blockIdx.x; n < N; n += gridDim.x){
    const float* h = nf + (size_t)n*256 + t*64;
    float sb = 0.f;
#pragma unroll
    for (int k = 0; k < 64; k += 4){
      float4 h4 = *(const float4*)(h + k);
      sb = fmaf(wd[k], h4.x, sb);
      sb = fmaf(wd[k+1], h4.y, sb);
      sb = fmaf(wd[k+2], h4.z, sb);
      sb = fmaf(wd[k+3], h4.w, sb);
    }
    B[(size_t)n*256 + c] = sb + bias;
    nfh[(size_t)n*256 + c] = (_Float16)nf[(size_t)n*256 + c];
  }
}

// ---------- aggregation v4: K=96 MFMA (Wsrc.h_src + Wef.ef), transposed f16 eps ----------
// Phase A: per 16-edge chunk, per-lane gather of h_src + streamed ef; 3 chained K=32
// MFMAs per colblock; D-frag (4 consecutive edges, fixed ch) stored as one 8B write
// into eps[ch][edge]. Phase B: thread=channel reads 4 edges per ds_read_b64; walk +
// FINALIZE identical to r11/r12 (validated). b0 commutes out as before.
__global__ __launch_bounds__(256) void k_agg(const int* __restrict__ offs, const int* __restrict__ esrc,
                                             const _Float16* __restrict__ efh,
                                             const _Float16* __restrict__ nfh, const float* __restrict__ B,
                                             const _Float16* __restrict__ Wall,
                                             ushort* __restrict__ X2, float* __restrict__ sc, int N, int E){
  __shared__ _Float16 eps[256][68];
  int tid = threadIdx.x;
  int lane = tid & 63, wv = tid >> 6;
  int li = lane & 15, kq = lane >> 4;
  int c = tid;                                  // this thread's channel
  int tw = c >> 6, d = c & 63;                  // tower, within-tower channel

  int n0 = blockIdx.x * NPB;
  if (n0 >= N) return;
  int n1 = n0 + NPB; if (n1 > N) n1 = N;
  int oS = offs[n0], oE = offs[n1];

  // B-fragments: wave wv = tower wv; bf[cb][slice]
  f16x8 bf[4][3];
#pragma unroll
  for (int cb = 0; cb < 4; ++cb)
#pragma unroll
    for (int sl = 0; sl < 3; ++sl)
      bf[cb][sl] = *(const f16x8*)(Wall + ((((size_t)wv*4 + cb)*3 + sl)*64 + lane)*8);

  int cur = n0;
  int curstart = oS;
  int nextoff = offs[n0 + 1];
  float s = 0.f, ss = 0.f;
  float mx = -__builtin_huge_valf(), mn = __builtin_huge_valf();

#define FINALIZE(CNT)                                                             \
  {                                                                                \
    float b = B[(size_t)cur*256 + c];                                              \
    float deg = (float)(CNT);                                                      \
    float degc = fmaxf(deg, 1.f);                                                  \
    float inv = 1.f / degc;                                                        \
    float S  = fmaf(deg, b, s);                                                    \
    float SS = fmaf(deg, b*b, fmaf(2.f*b, s, ss));                                 \
    float mean = S * inv;                                                          \
    float var  = fmaxf(SS * inv - mean*mean, 0.f);                                 \
    float sd   = sqrtf(var + 1e-30f);                                              \
    float MX = ((CNT) > 0) ? (b + mx) : 0.f;                                       \
    float MN = ((CNT) > 0) ? (b + mn) : 0.f;                                       \
    size_t xb = (((size_t)cur*4 + tw)*40)*16;                                      \
    { int kk = 64 + d;       ushort h2 = bf16h(mean);                              \
      X2[xb + (kk>>3)*16 + (kk&7)] = h2;                                           \
      X2[xb + (kk>>3)*16 + 8 + (kk&7)] = bf16h(mean - bf16f(h2)); }                \
    { int kk = 128 + d;      ushort h2 = bf16h(MX);                                \
      X2[xb + (kk>>3)*16 + (kk&7)] = h2;                                           \
      X2[xb + (kk>>3)*16 + 8 + (kk&7)] = bf16h(MX - bf16f(h2)); }                  \
    { int kk = 192 + d;      ushort h2 = bf16h(MN);                                \
      X2[xb + (kk>>3)*16 + (kk&7)] = h2;                                           \
      X2[xb + (kk>>3)*16 + 8 + (kk&7)] = bf16h(MN - bf16f(h2)); }                  \
    { int kk = 256 + d;      ushort h2 = bf16h(sd);                                \
      X2[xb + (kk>>3)*16 + (kk&7)] = h2;                                           \
      X2[xb + (kk>>3)*16 + 8 + (kk&7)] = bf16h(sd - bf16f(h2)); }                  \
    if (tid == 0){                                                                 \
      float logd = logf(deg + 1.f);                                                \
      sc[(size_t)cur*2]     = logd * (1.f / DELTA_);                               \
      sc[(size_t)cur*2 + 1] = ((CNT) > 0) ? (DELTA_ / fmaxf(logd, 1e-12f)) : 0.f;  \
    }                                                                              \
  }

  for (int w0 = oS; w0 < oE; w0 += 64){
    // ---- phase A: msg' for edges [w0, w0+64) via K=96 MFMA ----
    __syncthreads();
#pragma unroll
    for (int ch4 = 0; ch4 < 4; ++ch4){
      int pos = w0 + ch4*16 + li; if (pos > E - 1) pos = E - 1;
      int src = esrc[pos];
      const _Float16* hp = nfh + (size_t)src*256 + wv*64;
      f16x8 a0 = *(const f16x8*)(hp + kq*8);
      f16x8 a1 = *(const f16x8*)(hp + 32 + kq*8);
      f16x8 a2 = *(const f16x8*)(efh + (size_t)pos*32 + kq*8);
#pragma unroll
      for (int cb = 0; cb < 4; ++cb){
        f32x4 acc = __builtin_amdgcn_mfma_f32_16x16x32_f16(a0, bf[cb][0], (f32x4)0.f, 0, 0, 0);
        acc = __builtin_amdgcn_mfma_f32_16x16x32_f16(a1, bf[cb][1], acc, 0, 0, 0);
        acc = __builtin_amdgcn_mfma_f32_16x16x32_f16(a2, bf[cb][2], acc, 0, 0, 0);
        union { ushort4 u4; _Float16 h[4]; } st;
        st.h[0] = (_Float16)acc[0];
        st.h[1] = (_Float16)acc[1];
        st.h[2] = (_Float16)acc[2];
        st.h[3] = (_Float16)acc[3];
        *(ushort4*)(&eps[wv*64 + cb*16 + li][ch4*16 + kq*4]) = st.u4;
      }
    }
    __syncthreads();

    // ---- phase B: walk window edges, 4-edge vector LDS reads ----
    int wend = w0 + 64; if (wend > oE) wend = oE;
    for (int g = 0; g < 64; g += 4){
      if (w0 + g >= wend) break;
      union { ushort4 u4; _Float16 h[4]; } ld;
      ld.u4 = *(const ushort4*)(&eps[c][g]);
#pragma unroll
      for (int r = 0; r < 4; ++r){
        int idx = w0 + g + r;
        if (idx >= wend) break;
        while (idx == nextoff){
          FINALIZE(nextoff - curstart)
          curstart = nextoff;
          ++cur;
          nextoff = offs[cur + 1];
          s = 0.f; ss = 0.f;
          mx = -__builtin_huge_valf(); mn = __builtin_huge_valf();
        }
        float m = (float)ld.h[r];
        s += m;
        ss = fmaf(m, m, ss);
        mx = fmaxf(mx, m);
        mn = fminf(mn, m);
      }
    }
  }

  // tail: finalize remaining nodes (incl. zero-degree)
  while (cur < n1){
    FINALIZE(nextoff - curstart)
    curstart = nextoff;
    ++cur;
    if (cur < n1) nextoff = offs[cur + 1];
    s = 0.f; ss = 0.f;
    mx = -__builtin_huge_valf(); mn = __builtin_huge_valf();
  }
#undef FINALIZE
}

// ---------- U GEMM: LDS-free MFMA (round-8 form) ----------
__global__ __launch_bounds__(256) void k_u(const ushort* __restrict__ X2, const ushort* __restrict__ Wpk2,
                                           const float* __restrict__ sc, const float* __restrict__ Ub,
                                           float* __restrict__ uout, int Nn){
  __shared__ float su[64][68];
  int tid = threadIdx.x;
  int t   = blockIdx.y;
  int nbase = blockIdx.x*64;
  int lane = tid & 63, wv = tid >> 6;
  int li = lane & 15, kc = lane >> 4;
  int cbase = wv*48;

  f32x4 acc[4][3];
#pragma unroll
  for (int ri = 0; ri < 4; ++ri)
#pragma unroll
    for (int ci = 0; ci < 3; ++ci) acc[ri][ci] = (f32x4)0.f;

  const ushort* wb = Wpk2 + (size_t)t*192*320;

#pragma unroll 2
  for (int kt = 0; kt < 10; ++kt){
    bf16x8 ah[4], al[4], bh[3];
#pragma unroll
    for (int ri = 0; ri < 4; ++ri){
      int row = nbase + ri*16 + li;
      if (row >= Nn) row = Nn - 1;
      const ushort* ap = X2 + (((size_t)row*4 + t)*40 + kt*4 + kc)*16;
      ah[ri] = *(const bf16x8*)(ap);
      al[ri] = *(const bf16x8*)(ap + 8);
    }
#pragma unroll
    for (int ci = 0; ci < 3; ++ci){
      int col = cbase + ci*16 + li;
      bh[ci] = *(const bf16x8*)(wb + (size_t)col*320 + kt*32 + kc*8);
    }
#pragma unroll
    for (int ci = 0; ci < 3; ++ci)
#pragma unroll
      for (int ri = 0; ri < 4; ++ri){
        acc[ri][ci] = __builtin_amdgcn_mfma_f32_16x16x32_bf16(ah[ri], bh[ci], acc[ri][ci], 0, 0, 0);
        acc[ri][ci] = __builtin_amdgcn_mfma_f32_16x16x32_bf16(al[ri], bh[ci], acc[ri][ci], 0, 0, 0);
      }
  }

#define Y1_STORE(CI, OB) { _Pragma("unroll") for (int ri = 0; ri < 4; ++ri)               \
    { _Pragma("unroll") for (int r = 0; r < 4; ++r)                                        \
      su[ri*16 + kc*4 + r][(OB) + li] = acc[ri][CI][r]; } }
#define Y_ADD(CI, OB, SCOFF) { _Pragma("unroll") for (int ri = 0; ri < 4; ++ri)           \
    { _Pragma("unroll") for (int r = 0; r < 4; ++r){                                       \
      int node = ri*16 + kc*4 + r;                                                        \
      int gn = nbase + node; int gnc = (gn < Nn) ? gn : (Nn - 1);                          \
      float scl = sc[(size_t)gnc*2 + (SCOFF)];                                            \
      su[node][(OB) + li] += scl * acc[ri][CI][r]; } } }

  if (wv == 0){ Y1_STORE(0, 0)  Y1_STORE(1, 16) Y1_STORE(2, 32) }
  else if (wv == 1){ Y1_STORE(0, 48) }
  __syncthreads();
  if (wv == 1){ Y_ADD(1, 0, 0)  Y_ADD(2, 16, 0) }
  else if (wv == 2){ Y_ADD(0, 32, 0) Y_ADD(1, 48, 0) }
  __syncthreads();
  if (wv == 2){ Y_ADD(2, 0, 1) }
  else if (wv == 3){ Y_ADD(0, 16, 1) Y_ADD(1, 32, 1) Y_ADD(2, 48, 1) }
  __syncthreads();
#undef Y1_STORE
#undef Y_ADD

  for (int idx = tid; idx < 64*16; idx += 256){
    int n = idx >> 4, o4 = (idx & 15)*4;
    int gn = nbase + n;
    if (gn < Nn){
      float4 v = *(float4*)(&su[n][o4]);
      const float* ubp = Ub + t*64 + o4;
      v.x += ubp[0]; v.y += ubp[1]; v.z += ubp[2]; v.w += ubp[3];
      *(float4*)(&uout[(size_t)gn*256 + t*64 + o4]) = v;
    }
  }
}

// ---------- batchnorm stats (deterministic partials) ----------
__global__ __launch_bounds__(256) void k_bnstat(const float* __restrict__ u, float* __restrict__ part, int N){
  int c = threadIdx.x;
  int b = blockIdx.x;
  float s = 0.f, ss = 0.f;
  for (int n = b; n < N; n += gridDim.x){
    float v = u[(size_t)n*256 + c];
    s += v;
    ss = fmaf(v, v, ss);
  }
  part[(size_t)b*512 + c]       = s;
  part[(size_t)b*512 + 256 + c] = ss;
}

__global__ __launch_bounds__(256) void k_bnfin(const float* __restrict__ part, const float* __restrict__ gam,
                                               const float* __restrict__ bet, float* __restrict__ bnsc, int N){
  int c = threadIdx.x;
  float s = 0.f, ss = 0.f;
  for (int b = 0; b < BN_BLOCKS; ++b){
    s  += part[(size_t)b*512 + c];
    ss += part[(size_t)b*512 + 256 + c];
  }
  float invN = 1.f / (float)N;
  float mu  = s * invN;
  float ex2 = ss * invN;
  float var = fmaxf(ex2 - mu*mu, 0.f);
  float inv = 1.f / sqrtf(var + 1e-5f);
  float scale = gam[c] * inv;
  bnsc[c]       = scale;
  bnsc[256 + c] = bet[c] - mu*scale;
}

// ---------- X2m = bf16 hi/lo of (u*s + b), fragment-native [n][32][hi8|lo8] ----------
__global__ __launch_bounds__(256) void k_xm(const float* __restrict__ u, const float* __restrict__ bnsc,
                                            ushort* __restrict__ X2m, int N){
  for (long i = blockIdx.x*256 + threadIdx.x; i < (long)N*256; i += (long)gridDim.x*256){
    int n = (int)(i >> 8), c = (int)(i & 255);
    float v = fmaf(u[i], bnsc[c], bnsc[256 + c]);
    int j = c >> 3, pos = c & 7;
    size_t base = ((size_t)n*32 + j)*16;
    ushort hi = bf16h(v);
    X2m[base + pos]     = hi;
    X2m[base + 8 + pos] = bf16h(v - bf16f(hi));
  }
}

// ---------- mix GEMM: LDS-free MFMA + fused leaky/residual/relu ----------
__global__ __launch_bounds__(256) void k_mix(const ushort* __restrict__ X2m, const ushort* __restrict__ Wm2,
                                             const float* __restrict__ mixb, const float* __restrict__ nf,
                                             float* __restrict__ outp, int Nn){
  int tid = threadIdx.x;
  int nbase = blockIdx.x*64;
  int lane = tid & 63, wv = tid >> 6;
  int li = lane & 15, kc = lane >> 4;

  f32x4 acc[4][4];
#pragma unroll
  for (int ri = 0; ri < 4; ++ri)
#pragma unroll
    for (int ci = 0; ci < 4; ++ci) acc[ri][ci] = (f32x4)0.f;

#pragma unroll 2
  for (int kt = 0; kt < 8; ++kt){
    bf16x8 ah[4], al[4], bh[4];
#pragma unroll
    for (int ri = 0; ri < 4; ++ri){
      int row = nbase + ri*16 + li;
      if (row >= Nn) row = Nn - 1;
      const ushort* ap = X2m + (((size_t)row*32 + kt*4 + kc))*16;
      ah[ri] = *(const bf16x8*)(ap);
      al[ri] = *(const bf16x8*)(ap + 8);
    }
#pragma unroll
    for (int ci = 0; ci < 4; ++ci){
      int col = wv*64 + ci*16 + li;
      bh[ci] = *(const bf16x8*)(Wm2 + (size_t)col*256 + kt*32 + kc*8);
    }
#pragma unroll
    for (int ci = 0; ci < 4; ++ci)
#pragma unroll
      for (int ri = 0; ri < 4; ++ri){
        acc[ri][ci] = __builtin_amdgcn_mfma_f32_16x16x32_bf16(ah[ri], bh[ci], acc[ri][ci], 0, 0, 0);
        acc[ri][ci] = __builtin_amdgcn_mfma_f32_16x16x32_bf16(al[ri], bh[ci], acc[ri][ci], 0, 0, 0);
      }
  }

#pragma unroll
  for (int ri = 0; ri < 4; ++ri){
#pragma unroll
    for (int r = 0; r < 4; ++r){
      int node = ri*16 + kc*4 + r;
      int gn = nbase + node;
      if (gn < Nn){
#pragma unroll
        for (int ci = 0; ci < 4; ++ci){
          int col = wv*64 + ci*16 + li;
          float m = acc[ri][ci][r] + mixb[col];
          m = (m > 0.f) ? m : 0.01f*m;
          float o = m + nf[(size_t)gn*256 + col];
          outp[(size_t)gn*256 + col] = fmaxf(o, 0.f);
        }
      }
    }
  }
}

// ---------- host launcher ----------
extern "C" void kernel_launch(void* const* d_in, const int* in_sizes, int n_in,
                              void* d_out, int out_size, void* d_ws, size_t ws_size,
                              hipStream_t stream){
  const float* nf   = (const float*)d_in[0];
  const float* ef   = (const float*)d_in[1];
  const int*   srcv = (const int*)  d_in[2];
  const int*   dstv = (const int*)  d_in[3];
  const float* Mw   = (const float*)d_in[4];
  const float* Mb   = (const float*)d_in[5];
  const float* Uw   = (const float*)d_in[6];
  const float* Ub   = (const float*)d_in[7];
  const float* gam  = (const float*)d_in[8];
  const float* bet  = (const float*)d_in[9];
  const float* mixw = (const float*)d_in[10];
  const float* mixb = (const float*)d_in[11];
  int N = in_sizes[0] / 256;
  int E = in_sizes[2];
  float* out = (float*)d_out;

  char* wp = (char*)d_ws;
  auto alloc = [&](size_t bytes){
    char* p = wp;
    wp += (bytes + 1023) & ~(size_t)1023;
    return (void*)p;
  };
  int*      cnt   = (int*)     alloc((size_t)N*4);
  int*      offs  = (int*)     alloc((size_t)(N+1)*4);
  int*      cur   = (int*)     alloc((size_t)N*4);
  int*      bsum  = (int*)     alloc(256*4);
  int*      elist = (int*)     alloc((size_t)E*4);
  int*      esrc  = (int*)     alloc((size_t)E*4);
  // efh is dead after k_agg; X2m (written by k_xm) aliases it.
  size_t ealias   = (size_t)E*32*2;
  size_t malias   = (size_t)N*512*2;
  char*     shbuf = (char*)    alloc(ealias > malias ? ealias : malias);
  _Float16* efh   = (_Float16*)shbuf;
  ushort*   X2m   = (ushort*)  shbuf;
  _Float16* nfh   = (_Float16*)alloc((size_t)N*256*2);
  float*    B     = (float*)   alloc((size_t)N*256*4);
  float*    sc    = (float*)   alloc((size_t)N*2*4);
  float*    part  = (float*)   alloc((size_t)BN_BLOCKS*512*4);
  float*    bnsc  = (float*)   alloc(512*4);
  ushort*   X2    = (ushort*)  alloc((size_t)N*4*40*16*2);
  ushort*   Wpk2  = (ushort*)  alloc((size_t)4*192*320*2);
  ushort*   Wm2   = (ushort*)  alloc((size_t)256*256*2);
  _Float16* Wall  = (_Float16*)alloc((size_t)4*4*3*64*8*2);

  hipMemsetAsync(cnt,  0, (size_t)N*4,  stream);
  hipMemsetAsync(cur,  0, (size_t)N*4,  stream);

  k_tU  <<<(4*192*320 + 255)/256, 256, 0, stream>>>(Uw, Wpk2);
  k_tMm <<<(256*256 + 255)/256, 256, 0, stream>>>(mixw, Wm2);
  k_tW  <<<(4*4*3*64*8 + 255)/256, 256, 0, stream>>>(Mw, Wall);
  k_hist<<<(E + 255)/256, 256, 0, stream>>>(dstv, cnt, E);
  k_ab  <<<2048, 256, 0, stream>>>(nf, Mw, Mb, nfh, B, N);
  k_xh  <<<2048, 256, 0, stream>>>(nf, X2, N);

  int NB = (N + 255)/256;
  k_scan1<<<NB, 256, 0, stream>>>(cnt, offs, bsum, N);
  k_scan2<<<1, 256, 0, stream>>>(bsum, NB);
  k_scan3<<<NB, 256, 0, stream>>>(offs, bsum, N, E);
  k_fill <<<(E + 255)/256, 256, 0, stream>>>(dstv, offs, cur, elist, E);
  k_perm <<<(E*8 + 255)/256, 256, 0, stream>>>(elist, srcv, ef, esrc, efh, E);

  k_agg<<<(N + NPB - 1)/NPB, 256, 0, stream>>>(offs, esrc, efh, nfh, B, Wall, X2, sc, N, E);

  dim3 ugrid((N + 63)/64, 4);
  k_u<<<ugrid, 256, 0, stream>>>(X2, Wpk2, sc, Ub, out, N);

  k_bnstat<<<BN_BLOCKS, 256, 0, stream>>>(out, part, N);
  k_bnfin <<<1, 256, 0, stream>>>(part, gam, bet, bnsc, N);
  k_xm   <<<2048, 256, 0, stream>>>(out, bnsc, X2m, N);
  k_mix  <<<(N + 63)/64, 256, 0, stream>>>(X2m, Wm2, mixb, nf, out, N);
}

// Round 14
// 450.337 us; speedup vs baseline: 1.6876x; 1.0073x over previous
//
#include <hip/hip_runtime.h>
#include <math.h>

constexpr float DELTA_ = 2.5f;
#define BN_BLOCKS 512
#define NPB 8   // nodes per k_agg block

typedef __attribute__((ext_vector_type(8))) short bf16x8;
typedef __attribute__((ext_vector_type(8))) _Float16 f16x8;
typedef __attribute__((ext_vector_type(4))) float f32x4;

__device__ inline ushort bf16h(float x){
  union { float f; unsigned u; } v; v.f = x;
  unsigned r = v.u + 0x7fffu + ((v.u >> 16) & 1u);
  return (ushort)(r >> 16);
}
__device__ inline float bf16f(ushort h){
  union { unsigned u; float f; } v; v.u = ((unsigned)h) << 16;
  return v.f;
}

// ---------- U-weights: Wpk2[t][192][320] bf16 (col = path*64+o; path1/2 zero h-rows) ----------
__global__ __launch_bounds__(256) void k_tU(const float* __restrict__ Uw, ushort* __restrict__ Wpk2){
  int i = blockIdx.x*256 + threadIdx.x;          // i = (t*192+col)*320 + k
  if (i >= 4*192*320) return;
  int k   = i % 320;
  int col = (i/320) % 192;
  int t   = i/(320*192);
  int path = col >> 6, o = col & 63;
  float v = 0.f;
  int src = -1;
  if (k < 64){ if (path == 0) src = k; }
  else        src = k + path*256;
  if (src >= 0) v = Uw[((size_t)(t*64 + o))*832 + src];
  Wpk2[i] = bf16h(v);
}

// ---------- mix weights: Wm2[col][256] bf16 ----------
__global__ __launch_bounds__(256) void k_tMm(const float* __restrict__ mixw, ushort* __restrict__ Wm2){
  int i = blockIdx.x*256 + threadIdx.x;
  if (i >= 256*256) return;
  Wm2[i] = bf16h(mixw[i]);
}

// ---------- M-weights (W_src | W_ef) in B-fragment layout, K=96 ----------
__global__ __launch_bounds__(256) void k_tW(const float* __restrict__ Mw, _Float16* __restrict__ Wall){
  int i = blockIdx.x*256 + threadIdx.x;
  if (i >= 4*4*3*64*8) return;
  int j     = i & 7;
  int lane  = (i >> 3) & 63;
  int slice = (i / 512) % 3;
  int cb    = (i / 1536) % 4;
  int t     = i / 6144;
  int ch = t*64 + cb*16 + (lane & 15);
  int k  = slice*32 + ((lane >> 4) & 3)*8 + j;
  int off = (k < 64) ? k : (128 + (k - 64));
  Wall[i] = (_Float16)Mw[(size_t)ch*160 + off];
}

__global__ __launch_bounds__(256) void k_hist(const int* __restrict__ dstv, int* __restrict__ cnt, int E){
  int e = blockIdx.x*256 + threadIdx.x;
  if (e < E) atomicAdd(&cnt[dstv[e]], 1);
}

__global__ __launch_bounds__(256) void k_scan1(const int* __restrict__ cnt, int* __restrict__ offs,
                                               int* __restrict__ bsum, int N){
  __shared__ int lds[256];
  int i = threadIdx.x;
  int g = blockIdx.x*256 + i;
  int v = (g < N) ? cnt[g] : 0;
  int acc = v;
  lds[i] = acc; __syncthreads();
  for (int s = 1; s < 256; s <<= 1){
    int t = (i >= s) ? lds[i - s] : 0;
    __syncthreads();
    acc += t; lds[i] = acc;
    __syncthreads();
  }
  if (g < N) offs[g] = acc - v;
  if (i == 255) bsum[blockIdx.x] = acc;
}

__global__ __launch_bounds__(256) void k_scan2(int* __restrict__ bsum, int NB){
  __shared__ int lds[256];
  int i = threadIdx.x;
  int v = (i < NB) ? bsum[i] : 0;
  int acc = v;
  lds[i] = acc; __syncthreads();
  for (int s = 1; s < 256; s <<= 1){
    int t = (i >= s) ? lds[i - s] : 0;
    __syncthreads();
    acc += t; lds[i] = acc;
    __syncthreads();
  }
  if (i < NB) bsum[i] = acc - v;
}

__global__ __launch_bounds__(256) void k_scan3(int* __restrict__ offs, const int* __restrict__ bsum, int N, int E){
  int g = blockIdx.x*256 + threadIdx.x;
  if (g < N) offs[g] += bsum[blockIdx.x];
  if (g == 0) offs[N] = E;
}

__global__ __launch_bounds__(256) void k_fill(const int* __restrict__ dstv, const int* __restrict__ offs,
                                              int* __restrict__ cur, int* __restrict__ elist, int E){
  int e = blockIdx.x*256 + threadIdx.x;
  if (e < E){
    int d = dstv[e];
    elist[offs[d] + atomicAdd(&cur[d], 1)] = e;
  }
}

// ---------- permute srcv + edge features (f16) into CSR order ----------
__global__ __launch_bounds__(256) void k_perm(const int* __restrict__ elist, const int* __restrict__ srcv,
                                              const float* __restrict__ efeat,
                                              int* __restrict__ esrc, _Float16* __restrict__ efh, int E){
  int g = blockIdx.x*256 + threadIdx.x;
  int pos = g >> 3;
  int q   = g & 7;
  if (pos >= E) return;
  int e = elist[pos];
  if (q == 0) esrc[pos] = srcv[e];
  float4 v = *(const float4*)(efeat + (size_t)e*32 + q*4);
  union { ushort4 u; _Float16 h[4]; } cv;
  cv.h[0] = (_Float16)v.x; cv.h[1] = (_Float16)v.y;
  cv.h[2] = (_Float16)v.z; cv.h[3] = (_Float16)v.w;
  *(ushort4*)(efh + (size_t)pos*32 + q*4) = cv.u;
}

// ---------- nfh = f16(nf), B = W_dst*h + M_b, X2 h-part (fused, nf L1-hot) ----------
__global__ __launch_bounds__(256) void k_ab(const float* __restrict__ nf, const float* __restrict__ Mw,
                                            const float* __restrict__ Mb,
                                            _Float16* __restrict__ nfh, float* __restrict__ B,
                                            ushort* __restrict__ X2, int N){
  int c = threadIdx.x;
  int t = __builtin_amdgcn_readfirstlane(threadIdx.x >> 6);
  int d = c & 63;
  int jj = d >> 3, pp = d & 7;
  float wd[64];
  const float* row = Mw + (size_t)c*160 + 64;
#pragma unroll
  for (int k = 0; k < 64; k += 4){
    float4 b = *(const float4*)(row + k);
    wd[k]=b.x; wd[k+1]=b.y; wd[k+2]=b.z; wd[k+3]=b.w;
  }
  float bias = Mb[c];
  for (int n = blockIdx.x; n < N; n += gridDim.x){
    const float* h = nf + (size_t)n*256 + t*64;
    float sb = 0.f;
#pragma unroll
    for (int k = 0; k < 64; k += 4){
      float4 h4 = *(const float4*)(h + k);
      sb = fmaf(wd[k], h4.x, sb);
      sb = fmaf(wd[k+1], h4.y, sb);
      sb = fmaf(wd[k+2], h4.z, sb);
      sb = fmaf(wd[k+3], h4.w, sb);
    }
    B[(size_t)n*256 + c] = sb + bias;
    float v = nf[(size_t)n*256 + c];       // L1-hit (h tile just read)
    nfh[(size_t)n*256 + c] = (_Float16)v;
    ushort hi = bf16h(v);
    size_t base = (((size_t)n*4 + t)*40 + jj)*16;
    X2[base + pp]     = hi;
    X2[base + 8 + pp] = bf16h(v - bf16f(hi));
  }
}

// ---------- aggregation v4 (r13-validated): K=96 MFMA, transposed f16 eps ----------
__global__ __launch_bounds__(256) void k_agg(const int* __restrict__ offs, const int* __restrict__ esrc,
                                             const _Float16* __restrict__ efh,
                                             const _Float16* __restrict__ nfh, const float* __restrict__ B,
                                             const _Float16* __restrict__ Wall,
                                             ushort* __restrict__ X2, float* __restrict__ sc, int N, int E){
  __shared__ _Float16 eps[256][68];
  int tid = threadIdx.x;
  int lane = tid & 63, wv = tid >> 6;
  int li = lane & 15, kq = lane >> 4;
  int c = tid;
  int tw = c >> 6, d = c & 63;

  int n0 = blockIdx.x * NPB;
  if (n0 >= N) return;
  int n1 = n0 + NPB; if (n1 > N) n1 = N;
  int oS = offs[n0], oE = offs[n1];

  f16x8 bf[4][3];
#pragma unroll
  for (int cb = 0; cb < 4; ++cb)
#pragma unroll
    for (int sl = 0; sl < 3; ++sl)
      bf[cb][sl] = *(const f16x8*)(Wall + ((((size_t)wv*4 + cb)*3 + sl)*64 + lane)*8);

  int cur = n0;
  int curstart = oS;
  int nextoff = offs[n0 + 1];
  float s = 0.f, ss = 0.f;
  float mx = -__builtin_huge_valf(), mn = __builtin_huge_valf();

#define FINALIZE(CNT)                                                             \
  {                                                                                \
    float b = B[(size_t)cur*256 + c];                                              \
    float deg = (float)(CNT);                                                      \
    float degc = fmaxf(deg, 1.f);                                                  \
    float inv = 1.f / degc;                                                        \
    float S  = fmaf(deg, b, s);                                                    \
    float SS = fmaf(deg, b*b, fmaf(2.f*b, s, ss));                                 \
    float mean = S * inv;                                                          \
    float var  = fmaxf(SS * inv - mean*mean, 0.f);                                 \
    float sd   = sqrtf(var + 1e-30f);                                              \
    float MX = ((CNT) > 0) ? (b + mx) : 0.f;                                       \
    float MN = ((CNT) > 0) ? (b + mn) : 0.f;                                       \
    size_t xb = (((size_t)cur*4 + tw)*40)*16;                                      \
    { int kk = 64 + d;       ushort h2 = bf16h(mean);                              \
      X2[xb + (kk>>3)*16 + (kk&7)] = h2;                                           \
      X2[xb + (kk>>3)*16 + 8 + (kk&7)] = bf16h(mean - bf16f(h2)); }                \
    { int kk = 128 + d;      ushort h2 = bf16h(MX);                                \
      X2[xb + (kk>>3)*16 + (kk&7)] = h2;                                           \
      X2[xb + (kk>>3)*16 + 8 + (kk&7)] = bf16h(MX - bf16f(h2)); }                  \
    { int kk = 192 + d;      ushort h2 = bf16h(MN);                                \
      X2[xb + (kk>>3)*16 + (kk&7)] = h2;                                           \
      X2[xb + (kk>>3)*16 + 8 + (kk&7)] = bf16h(MN - bf16f(h2)); }                  \
    { int kk = 256 + d;      ushort h2 = bf16h(sd);                                \
      X2[xb + (kk>>3)*16 + (kk&7)] = h2;                                           \
      X2[xb + (kk>>3)*16 + 8 + (kk&7)] = bf16h(sd - bf16f(h2)); }                  \
    if (tid == 0){                                                                 \
      float logd = logf(deg + 1.f);                                                \
      sc[(size_t)cur*2]     = logd * (1.f / DELTA_);                               \
      sc[(size_t)cur*2 + 1] = ((CNT) > 0) ? (DELTA_ / fmaxf(logd, 1e-12f)) : 0.f;  \
    }                                                                              \
  }

  for (int w0 = oS; w0 < oE; w0 += 64){
    __syncthreads();
#pragma unroll
    for (int ch4 = 0; ch4 < 4; ++ch4){
      int pos = w0 + ch4*16 + li; if (pos > E - 1) pos = E - 1;
      int src = esrc[pos];
      const _Float16* hp = nfh + (size_t)src*256 + wv*64;
      f16x8 a0 = *(const f16x8*)(hp + kq*8);
      f16x8 a1 = *(const f16x8*)(hp + 32 + kq*8);
      f16x8 a2 = *(const f16x8*)(efh + (size_t)pos*32 + kq*8);
#pragma unroll
      for (int cb = 0; cb < 4; ++cb){
        f32x4 acc = __builtin_amdgcn_mfma_f32_16x16x32_f16(a0, bf[cb][0], (f32x4)0.f, 0, 0, 0);
        acc = __builtin_amdgcn_mfma_f32_16x16x32_f16(a1, bf[cb][1], acc, 0, 0, 0);
        acc = __builtin_amdgcn_mfma_f32_16x16x32_f16(a2, bf[cb][2], acc, 0, 0, 0);
        union { ushort4 u4; _Float16 h[4]; } st;
        st.h[0] = (_Float16)acc[0];
        st.h[1] = (_Float16)acc[1];
        st.h[2] = (_Float16)acc[2];
        st.h[3] = (_Float16)acc[3];
        *(ushort4*)(&eps[wv*64 + cb*16 + li][ch4*16 + kq*4]) = st.u4;
      }
    }
    __syncthreads();

    int wend = w0 + 64; if (wend > oE) wend = oE;
    for (int g = 0; g < 64; g += 4){
      if (w0 + g >= wend) break;
      union { ushort4 u4; _Float16 h[4]; } ld;
      ld.u4 = *(const ushort4*)(&eps[c][g]);
#pragma unroll
      for (int r = 0; r < 4; ++r){
        int idx = w0 + g + r;
        if (idx >= wend) break;
        while (idx == nextoff){
          FINALIZE(nextoff - curstart)
          curstart = nextoff;
          ++cur;
          nextoff = offs[cur + 1];
          s = 0.f; ss = 0.f;
          mx = -__builtin_huge_valf(); mn = __builtin_huge_valf();
        }
        float m = (float)ld.h[r];
        s += m;
        ss = fmaf(m, m, ss);
        mx = fmaxf(mx, m);
        mn = fminf(mn, m);
      }
    }
  }

  while (cur < n1){
    FINALIZE(nextoff - curstart)
    curstart = nextoff;
    ++cur;
    if (cur < n1) nextoff = offs[cur + 1];
    s = 0.f; ss = 0.f;
    mx = -__builtin_huge_valf(); mn = __builtin_huge_valf();
  }
#undef FINALIZE
}

// ---------- U GEMM: LDS-free MFMA (round-8 form) ----------
__global__ __launch_bounds__(256) void k_u(const ushort* __restrict__ X2, const ushort* __restrict__ Wpk2,
                                           const float* __restrict__ sc, const float* __restrict__ Ub,
                                           float* __restrict__ uout, int Nn){
  __shared__ float su[64][68];
  int tid = threadIdx.x;
  int t   = blockIdx.y;
  int nbase = blockIdx.x*64;
  int lane = tid & 63, wv = tid >> 6;
  int li = lane & 15, kc = lane >> 4;
  int cbase = wv*48;

  f32x4 acc[4][3];
#pragma unroll
  for (int ri = 0; ri < 4; ++ri)
#pragma unroll
    for (int ci = 0; ci < 3; ++ci) acc[ri][ci] = (f32x4)0.f;

  const ushort* wb = Wpk2 + (size_t)t*192*320;

#pragma unroll 2
  for (int kt = 0; kt < 10; ++kt){
    bf16x8 ah[4], al[4], bh[3];
#pragma unroll
    for (int ri = 0; ri < 4; ++ri){
      int row = nbase + ri*16 + li;
      if (row >= Nn) row = Nn - 1;
      const ushort* ap = X2 + (((size_t)row*4 + t)*40 + kt*4 + kc)*16;
      ah[ri] = *(const bf16x8*)(ap);
      al[ri] = *(const bf16x8*)(ap + 8);
    }
#pragma unroll
    for (int ci = 0; ci < 3; ++ci){
      int col = cbase + ci*16 + li;
      bh[ci] = *(const bf16x8*)(wb + (size_t)col*320 + kt*32 + kc*8);
    }
#pragma unroll
    for (int ci = 0; ci < 3; ++ci)
#pragma unroll
      for (int ri = 0; ri < 4; ++ri){
        acc[ri][ci] = __builtin_amdgcn_mfma_f32_16x16x32_bf16(ah[ri], bh[ci], acc[ri][ci], 0, 0, 0);
        acc[ri][ci] = __builtin_amdgcn_mfma_f32_16x16x32_bf16(al[ri], bh[ci], acc[ri][ci], 0, 0, 0);
      }
  }

#define Y1_STORE(CI, OB) { _Pragma("unroll") for (int ri = 0; ri < 4; ++ri)               \
    { _Pragma("unroll") for (int r = 0; r < 4; ++r)                                        \
      su[ri*16 + kc*4 + r][(OB) + li] = acc[ri][CI][r]; } }
#define Y_ADD(CI, OB, SCOFF) { _Pragma("unroll") for (int ri = 0; ri < 4; ++ri)           \
    { _Pragma("unroll") for (int r = 0; r < 4; ++r){                                       \
      int node = ri*16 + kc*4 + r;                                                        \
      int gn = nbase + node; int gnc = (gn < Nn) ? gn : (Nn - 1);                          \
      float scl = sc[(size_t)gnc*2 + (SCOFF)];                                            \
      su[node][(OB) + li] += scl * acc[ri][CI][r]; } } }

  if (wv == 0){ Y1_STORE(0, 0)  Y1_STORE(1, 16) Y1_STORE(2, 32) }
  else if (wv == 1){ Y1_STORE(0, 48) }
  __syncthreads();
  if (wv == 1){ Y_ADD(1, 0, 0)  Y_ADD(2, 16, 0) }
  else if (wv == 2){ Y_ADD(0, 32, 0) Y_ADD(1, 48, 0) }
  __syncthreads();
  if (wv == 2){ Y_ADD(2, 0, 1) }
  else if (wv == 3){ Y_ADD(0, 16, 1) Y_ADD(1, 32, 1) Y_ADD(2, 48, 1) }
  __syncthreads();
#undef Y1_STORE
#undef Y_ADD

  for (int idx = tid; idx < 64*16; idx += 256){
    int n = idx >> 4, o4 = (idx & 15)*4;
    int gn = nbase + n;
    if (gn < Nn){
      float4 v = *(float4*)(&su[n][o4]);
      const float* ubp = Ub + t*64 + o4;
      v.x += ubp[0]; v.y += ubp[1]; v.z += ubp[2]; v.w += ubp[3];
      *(float4*)(&uout[(size_t)gn*256 + t*64 + o4]) = v;
    }
  }
}

// ---------- batchnorm stats (deterministic partials) ----------
__global__ __launch_bounds__(256) void k_bnstat(const float* __restrict__ u, float* __restrict__ part, int N){
  int c = threadIdx.x;
  int b = blockIdx.x;
  float s = 0.f, ss = 0.f;
  for (int n = b; n < N; n += gridDim.x){
    float v = u[(size_t)n*256 + c];
    s += v;
    ss = fmaf(v, v, ss);
  }
  part[(size_t)b*512 + c]       = s;
  part[(size_t)b*512 + 256 + c] = ss;
}

__global__ __launch_bounds__(256) void k_bnfin(const float* __restrict__ part, const float* __restrict__ gam,
                                               const float* __restrict__ bet, float* __restrict__ bnsc, int N){
  int c = threadIdx.x;
  float s = 0.f, ss = 0.f;
  for (int b = 0; b < BN_BLOCKS; ++b){
    s  += part[(size_t)b*512 + c];
    ss += part[(size_t)b*512 + 256 + c];
  }
  float invN = 1.f / (float)N;
  float mu  = s * invN;
  float ex2 = ss * invN;
  float var = fmaxf(ex2 - mu*mu, 0.f);
  float inv = 1.f / sqrtf(var + 1e-5f);
  float scale = gam[c] * inv;
  bnsc[c]       = scale;
  bnsc[256 + c] = bet[c] - mu*scale;
}

// ---------- mix GEMM: reads u directly (BN folded in-reg), fused epilogue ----------
// Each block touches ONLY its own 64 u-rows; all reads precede the barrier,
// writes (in-place over u) follow it.
__global__ __launch_bounds__(256) void k_mix(const float* __restrict__ u, const ushort* __restrict__ Wm2,
                                             const float* __restrict__ bnsc,
                                             const float* __restrict__ mixb, const float* __restrict__ nf,
                                             float* __restrict__ outp, int Nn){
  int tid = threadIdx.x;
  int nbase = blockIdx.x*64;
  int lane = tid & 63, wv = tid >> 6;
  int li = lane & 15, kc = lane >> 4;

  f32x4 acc[4][4];
#pragma unroll
  for (int ri = 0; ri < 4; ++ri)
#pragma unroll
    for (int ci = 0; ci < 4; ++ci) acc[ri][ci] = (f32x4)0.f;

#pragma unroll 2
  for (int kt = 0; kt < 8; ++kt){
    int k0 = kt*32 + kc*8;
    float4 s40 = *(const float4*)(bnsc + k0);
    float4 s41 = *(const float4*)(bnsc + k0 + 4);
    float4 h40 = *(const float4*)(bnsc + 256 + k0);
    float4 h41 = *(const float4*)(bnsc + 256 + k0 + 4);
    bf16x8 ah[4], al[4], bh[4];
#pragma unroll
    for (int ri = 0; ri < 4; ++ri){
      int row = nbase + ri*16 + li;
      if (row >= Nn) row = Nn - 1;
      const float* up = u + (size_t)row*256 + k0;
      float4 v0 = *(const float4*)(up);
      float4 v1 = *(const float4*)(up + 4);
      float x[8];
      x[0] = fmaf(v0.x, s40.x, h40.x); x[1] = fmaf(v0.y, s40.y, h40.y);
      x[2] = fmaf(v0.z, s40.z, h40.z); x[3] = fmaf(v0.w, s40.w, h40.w);
      x[4] = fmaf(v1.x, s41.x, h41.x); x[5] = fmaf(v1.y, s41.y, h41.y);
      x[6] = fmaf(v1.z, s41.z, h41.z); x[7] = fmaf(v1.w, s41.w, h41.w);
      union { bf16x8 v; ushort u[8]; } hh, ll;
#pragma unroll
      for (int q = 0; q < 8; ++q){
        ushort hb = bf16h(x[q]);
        hh.u[q] = hb;
        ll.u[q] = bf16h(x[q] - bf16f(hb));
      }
      ah[ri] = hh.v;
      al[ri] = ll.v;
    }
#pragma unroll
    for (int ci = 0; ci < 4; ++ci){
      int col = wv*64 + ci*16 + li;
      bh[ci] = *(const bf16x8*)(Wm2 + (size_t)col*256 + kt*32 + kc*8);
    }
#pragma unroll
    for (int ci = 0; ci < 4; ++ci)
#pragma unroll
      for (int ri = 0; ri < 4; ++ri){
        acc[ri][ci] = __builtin_amdgcn_mfma_f32_16x16x32_bf16(ah[ri], bh[ci], acc[ri][ci], 0, 0, 0);
        acc[ri][ci] = __builtin_amdgcn_mfma_f32_16x16x32_bf16(al[ri], bh[ci], acc[ri][ci], 0, 0, 0);
      }
  }

  __syncthreads();   // all reads of u done before any in-place write
#pragma unroll
  for (int ri = 0; ri < 4; ++ri){
#pragma unroll
    for (int r = 0; r < 4; ++r){
      int node = ri*16 + kc*4 + r;
      int gn = nbase + node;
      if (gn < Nn){
#pragma unroll
        for (int ci = 0; ci < 4; ++ci){
          int col = wv*64 + ci*16 + li;
          float m = acc[ri][ci][r] + mixb[col];
          m = (m > 0.f) ? m : 0.01f*m;
          float o = m + nf[(size_t)gn*256 + col];
          outp[(size_t)gn*256 + col] = fmaxf(o, 0.f);
        }
      }
    }
  }
}

// ---------- host launcher ----------
extern "C" void kernel_launch(void* const* d_in, const int* in_sizes, int n_in,
                              void* d_out, int out_size, void* d_ws, size_t ws_size,
                              hipStream_t stream){
  const float* nf   = (const float*)d_in[0];
  const float* ef   = (const float*)d_in[1];
  const int*   srcv = (const int*)  d_in[2];
  const int*   dstv = (const int*)  d_in[3];
  const float* Mw   = (const float*)d_in[4];
  const float* Mb   = (const float*)d_in[5];
  const float* Uw   = (const float*)d_in[6];
  const float* Ub   = (const float*)d_in[7];
  const float* gam  = (const float*)d_in[8];
  const float* bet  = (const float*)d_in[9];
  const float* mixw = (const float*)d_in[10];
  const float* mixb = (const float*)d_in[11];
  int N = in_sizes[0] / 256;
  int E = in_sizes[2];
  float* out = (float*)d_out;

  char* wp = (char*)d_ws;
  auto alloc = [&](size_t bytes){
    char* p = wp;
    wp += (bytes + 1023) & ~(size_t)1023;
    return (void*)p;
  };
  int*      cnt   = (int*)     alloc((size_t)N*4);
  int*      offs  = (int*)     alloc((size_t)(N+1)*4);
  int*      cur   = (int*)     alloc((size_t)N*4);
  int*      bsum  = (int*)     alloc(256*4);
  int*      elist = (int*)     alloc((size_t)E*4);
  int*      esrc  = (int*)     alloc((size_t)E*4);
  _Float16* efh   = (_Float16*)alloc((size_t)E*32*2);
  _Float16* nfh   = (_Float16*)alloc((size_t)N*256*2);
  float*    B     = (float*)   alloc((size_t)N*256*4);
  float*    sc    = (float*)   alloc((size_t)N*2*4);
  float*    part  = (float*)   alloc((size_t)BN_BLOCKS*512*4);
  float*    bnsc  = (float*)   alloc(512*4);
  ushort*   X2    = (ushort*)  alloc((size_t)N*4*40*16*2);
  ushort*   Wpk2  = (ushort*)  alloc((size_t)4*192*320*2);
  ushort*   Wm2   = (ushort*)  alloc((size_t)256*256*2);
  _Float16* Wall  = (_Float16*)alloc((size_t)4*4*3*64*8*2);

  hipMemsetAsync(cnt,  0, (size_t)N*4,  stream);
  hipMemsetAsync(cur,  0, (size_t)N*4,  stream);

  k_tU  <<<(4*192*320 + 255)/256, 256, 0, stream>>>(Uw, Wpk2);
  k_tMm <<<(256*256 + 255)/256, 256, 0, stream>>>(mixw, Wm2);
  k_tW  <<<(4*4*3*64*8 + 255)/256, 256, 0, stream>>>(Mw, Wall);
  k_hist<<<(E + 255)/256, 256, 0, stream>>>(dstv, cnt, E);
  k_ab  <<<2048, 256, 0, stream>>>(nf, Mw, Mb, nfh, B, X2, N);

  int NB = (N + 255)/256;
  k_scan1<<<NB, 256, 0, stream>>>(cnt, offs, bsum, N);
  k_scan2<<<1, 256, 0, stream>>>(bsum, NB);
  k_scan3<<<NB, 256, 0, stream>>>(offs, bsum, N, E);
  k_fill <<<(E + 255)/256, 256, 0, stream>>>(dstv, offs, cur, elist, E);
  k_perm <<<(E*8 + 255)/256, 256, 0, stream>>>(elist, srcv, ef, esrc, efh, E);

  k_agg<<<(N + NPB - 1)/NPB, 256, 0, stream>>>(offs, esrc, efh, nfh, B, Wall, X2, sc, N, E);

  dim3 ugrid((N + 63)/64, 4);
  k_u<<<ugrid, 256, 0, stream>>>(X2, Wpk2, sc, Ub, out, N);

  k_bnstat<<<BN_BLOCKS, 256, 0, stream>>>(out, part, N);
  k_bnfin <<<1, 256, 0, stream>>>(part, gam, bet, bnsc, N);
  k_mix  <<<(N + 63)/64, 256, 0, stream>>>(out, Wm2, bnsc, mixb, nf, out, N);
}